// Round 1
// baseline (2108.225 us; speedup 1.0000x reference)
//
#include <hip/hip_runtime.h>
#include <math.h>

// Problem shape (fixed by setup_inputs)
constexpr int Bb  = 4;
constexpr int L   = 4096;
constexpr int Dm  = 2048;
constexpr int S   = 512;
constexpr int KC  = 4;            // conv taps
constexpr int M   = Bb * L;       // 16384 rows
constexpr int NP  = 2 * S + 1;    // 1025 proj cols
constexpr int CL  = 128;          // scan chunk length
constexpr int NCH = L / CL;       // 32 chunks

// GEMM tiling
#define BM 128
#define BN 128
#define BK 16
#define LDP 132   // padded LDS leading dim (multiple of 4 -> float4-aligned)

// ---------------------------------------------------------------------------
// causal depthwise conv: xc[b,l,d] = bias[d] + sum_k x[b,l-3+k,d]*w[d,k]
// ---------------------------------------------------------------------------
__global__ __launch_bounds__(256)
void conv_kernel(const float* __restrict__ x, const float* __restrict__ w,
                 const float* __restrict__ bias, float* __restrict__ xc)
{
    const int total4 = M * (Dm / 4);
    const float4* x4 = (const float4*)x;
    float4* xc4 = (float4*)xc;
    for (int i = blockIdx.x * blockDim.x + threadIdx.x; i < total4;
         i += gridDim.x * blockDim.x) {
        int d4 = i & (Dm / 4 - 1);
        int m  = i >> 9;            // /(Dm/4)
        int l  = m & (L - 1);
        int d  = d4 * 4;
        float w0[4], w1[4], w2[4], w3[4];
        *(float4*)w0 = *(const float4*)&w[(d + 0) * 4];
        *(float4*)w1 = *(const float4*)&w[(d + 1) * 4];
        *(float4*)w2 = *(const float4*)&w[(d + 2) * 4];
        *(float4*)w3 = *(const float4*)&w[(d + 3) * 4];
        float4 acc;
        acc.x = bias[d + 0]; acc.y = bias[d + 1];
        acc.z = bias[d + 2]; acc.w = bias[d + 3];
        #pragma unroll
        for (int k = 0; k < KC; ++k) {
            int lp = l - (KC - 1) + k;
            if (lp >= 0) {
                float4 xv = x4[(size_t)(m - (KC - 1) + k) * (Dm / 4) + d4];
                acc.x = fmaf(xv.x, w0[k], acc.x);
                acc.y = fmaf(xv.y, w1[k], acc.y);
                acc.z = fmaf(xv.z, w2[k], acc.z);
                acc.w = fmaf(xv.w, w3[k], acc.w);
            }
        }
        xc4[i] = acc;
    }
}

// ---------------------------------------------------------------------------
// delta[m] = softplus(params[m, 2S])
// ---------------------------------------------------------------------------
__global__ __launch_bounds__(256)
void delta_kernel(const float* __restrict__ params, float* __restrict__ delta)
{
    int i = blockIdx.x * 256 + threadIdx.x;
    if (i < M) {
        float z = params[(size_t)i * NP + 2 * S];
        delta[i] = (z > 20.f) ? z : log1pf(__expf(z));
    }
}

// ---------------------------------------------------------------------------
// C(M,N) = A(M,K) @ B(N,K)^T  with fused epilogues.
// EPI 0: plain store (ssm_params)
// EPI 1: C = delta[m] * Bmat[m,n] * acc   (Bu;  e0=delta, e1=params)
// EPI 2: C = acc + e0[n] * e1[m*N+n]      (out; e0=D,     e1=x_conv)
// ---------------------------------------------------------------------------
template <int EPI>
__global__ __launch_bounds__(256)
void gemm_abt(const float* __restrict__ A, const float* __restrict__ B,
              float* __restrict__ C, int N, int K,
              const float* __restrict__ e0, const float* __restrict__ e1)
{
    __shared__ float As[BK][LDP];
    __shared__ float Bs[BK][LDP];
    const int tid  = threadIdx.x;
    const int row0 = blockIdx.x * BM;
    const int col0 = blockIdx.y * BN;

    float acc[8][8];
    #pragma unroll
    for (int i = 0; i < 8; ++i)
        #pragma unroll
        for (int j = 0; j < 8; ++j) acc[i][j] = 0.f;

    const int ty = tid >> 4, tx = tid & 15;
    const int m0 = ty * 8, n0 = tx * 8;

    for (int k0 = 0; k0 < K; k0 += BK) {
        float4 va[2], vb[2];
        int rowT[2], kk[2];
        #pragma unroll
        for (int i = 0; i < 2; ++i) {
            int f4 = tid + i * 256;
            int r  = f4 >> 2;
            int k4 = f4 & 3;
            rowT[i] = r; kk[i] = k4 * 4;
            va[i] = *((const float4*)(A + (size_t)(row0 + r) * K + k0 + k4 * 4));
            int nb = col0 + r;
            if (nb < N)
                vb[i] = *((const float4*)(B + (size_t)nb * K + k0 + k4 * 4));
            else
                vb[i] = make_float4(0.f, 0.f, 0.f, 0.f);
        }
        __syncthreads();   // prior compute done before overwriting LDS
        #pragma unroll
        for (int i = 0; i < 2; ++i) {
            As[kk[i] + 0][rowT[i]] = va[i].x;
            As[kk[i] + 1][rowT[i]] = va[i].y;
            As[kk[i] + 2][rowT[i]] = va[i].z;
            As[kk[i] + 3][rowT[i]] = va[i].w;
            Bs[kk[i] + 0][rowT[i]] = vb[i].x;
            Bs[kk[i] + 1][rowT[i]] = vb[i].y;
            Bs[kk[i] + 2][rowT[i]] = vb[i].z;
            Bs[kk[i] + 3][rowT[i]] = vb[i].w;
        }
        __syncthreads();
        #pragma unroll
        for (int k = 0; k < BK; ++k) {
            float a[8], bq[8];
            *(float4*)&a[0]  = *(const float4*)&As[k][m0];
            *(float4*)&a[4]  = *(const float4*)&As[k][m0 + 4];
            *(float4*)&bq[0] = *(const float4*)&Bs[k][n0];
            *(float4*)&bq[4] = *(const float4*)&Bs[k][n0 + 4];
            #pragma unroll
            for (int i = 0; i < 8; ++i)
                #pragma unroll
                for (int j = 0; j < 8; ++j)
                    acc[i][j] = fmaf(a[i], bq[j], acc[i][j]);
        }
    }

    #pragma unroll
    for (int i = 0; i < 8; ++i) {
        int mr = row0 + m0 + i;
        #pragma unroll
        for (int j = 0; j < 8; ++j) {
            int nc = col0 + n0 + j;
            if (nc >= N) continue;
            float v = acc[i][j];
            if (EPI == 0) {
                C[(size_t)mr * N + nc] = v;
            } else if (EPI == 1) {
                float dl = e0[mr];
                float Bm = e1[(size_t)mr * NP + nc];
                C[(size_t)mr * N + nc] = dl * Bm * v;
            } else {
                C[(size_t)mr * N + nc] = v + e0[nc] * e1[(size_t)mr * N + nc];
            }
        }
    }
}

// ---------------------------------------------------------------------------
// chunked scan: h[l] = a[l]*h[l-1] + u[l],  a = exp(-exp(A_log[s]) * delta[l])
// pass1: per-chunk (prod a, h_end)
// ---------------------------------------------------------------------------
__global__ __launch_bounds__(256)
void scan_pass1(const float* __restrict__ Bu, const float* __restrict__ delta,
                const float* __restrict__ A_log,
                float* __restrict__ cP, float* __restrict__ cH)
{
    int s = blockIdx.x * 256 + threadIdx.x;
    int c = blockIdx.y;
    int b = blockIdx.z;
    float Acoef = -expf(A_log[s]);
    float P = 1.f, h = 0.f;
    int mbase = b * L + c * CL;
    for (int t = 0; t < CL; ++t) {
        float a = __expf(Acoef * delta[mbase + t]);
        float u = Bu[(size_t)(mbase + t) * S + s];
        h = fmaf(a, h, u);
        P *= a;
    }
    int id = b * S + s;
    cP[(size_t)id * NCH + c] = P;
    cH[(size_t)id * NCH + c] = h;
}

// pass2: sequential combine over chunks -> per-chunk initial h
__global__ __launch_bounds__(256)
void scan_pass2(const float* __restrict__ cP, const float* __restrict__ cH,
                float* __restrict__ init)
{
    int id = blockIdx.x * 256 + threadIdx.x;
    if (id < Bb * S) {
        float h = 0.f;
        for (int c = 0; c < NCH; ++c) {
            init[(size_t)id * NCH + c] = h;
            h = fmaf(cP[(size_t)id * NCH + c], h, cH[(size_t)id * NCH + c]);
        }
    }
}

// pass3: rescan with initial h; write h_mod = Cmat * h  in place over Bu
__global__ __launch_bounds__(256)
void scan_pass3(float* __restrict__ Bu, const float* __restrict__ delta,
                const float* __restrict__ params, const float* __restrict__ A_log,
                const float* __restrict__ init)
{
    int s = blockIdx.x * 256 + threadIdx.x;
    int c = blockIdx.y;
    int b = blockIdx.z;
    float Acoef = -expf(A_log[s]);
    float h = init[(size_t)(b * S + s) * NCH + c];
    int mbase = b * L + c * CL;
    for (int t = 0; t < CL; ++t) {
        int m = mbase + t;
        float a = __expf(Acoef * delta[m]);
        size_t bi = (size_t)m * S + s;
        float u = Bu[bi];
        h = fmaf(a, h, u);
        float Cm = params[(size_t)m * NP + S + s];
        Bu[bi] = Cm * h;
    }
}

// ---------------------------------------------------------------------------
extern "C" void kernel_launch(void* const* d_in, const int* in_sizes, int n_in,
                              void* d_out, int out_size, void* d_ws, size_t ws_size,
                              hipStream_t stream)
{
    const float* x        = (const float*)d_in[0];
    const float* Wxproj   = (const float*)d_in[1];
    const float* Winproj  = (const float*)d_in[2];
    const float* Woutproj = (const float*)d_in[3];
    const float* conv_w   = (const float*)d_in[4];
    const float* conv_b   = (const float*)d_in[5];
    const float* A_log    = (const float*)d_in[6];
    const float* Dvec     = (const float*)d_in[7];
    float* out = (float*)d_out;

    float* ws        = (float*)d_ws;
    float* ws_params = ws;                                  // M*NP   = 16.79M f
    float* ws_xconv  = ws_params + (size_t)M * NP;          // M*Dm   = 33.55M f
    float* ws_Bu     = ws_xconv + (size_t)M * Dm;           // M*S    =  8.39M f
    float* ws_delta  = ws_Bu + (size_t)M * S;               // M
    float* ws_cP     = ws_delta + M;                        // B*S*NCH
    float* ws_cH     = ws_cP + (size_t)Bb * S * NCH;
    float* ws_init   = ws_cH + (size_t)Bb * S * NCH;

    // 1. depthwise causal conv -> x_conv
    conv_kernel<<<2048, 256, 0, stream>>>(x, conv_w, conv_b, ws_xconv);

    // 2. ssm_params = x @ Wxproj^T   (M x 1025)
    dim3 g1(M / BM, (NP + BN - 1) / BN);
    gemm_abt<0><<<g1, 256, 0, stream>>>(x, Wxproj, ws_params, NP, Dm,
                                        nullptr, nullptr);

    // 3. delta = softplus(params[:, 2S])
    delta_kernel<<<M / 256, 256, 0, stream>>>(ws_params, ws_delta);

    // 4. Bu = delta * Bmat * (x_conv @ Winproj^T)   (M x 512)
    dim3 g2(M / BM, S / BN);
    gemm_abt<1><<<g2, 256, 0, stream>>>(ws_xconv, Winproj, ws_Bu, S, Dm,
                                        ws_delta, ws_params);

    // 5. chunked associative scan over L; h_mod = Cmat*h written over Bu
    dim3 gs(S / 256, NCH, Bb);
    scan_pass1<<<gs, 256, 0, stream>>>(ws_Bu, ws_delta, A_log, ws_cP, ws_cH);
    scan_pass2<<<(Bb * S) / 256, 256, 0, stream>>>(ws_cP, ws_cH, ws_init);
    scan_pass3<<<gs, 256, 0, stream>>>(ws_Bu, ws_delta, ws_params, A_log, ws_init);

    // 6. out = h_mod @ Woutproj^T + D * x_conv   (M x 2048)
    dim3 g3(M / BM, Dm / BN);
    gemm_abt<2><<<g3, 256, 0, stream>>>(ws_Bu, Woutproj, out, Dm, S,
                                        Dvec, ws_xconv);
}

// Round 3
// 553.068 us; speedup vs baseline: 3.8119x; 3.8119x over previous
//
#include <hip/hip_runtime.h>
#include <math.h>

typedef __bf16 bf16_t;
typedef __bf16 bf16x8 __attribute__((ext_vector_type(8)));
typedef __bf16 bf16x4 __attribute__((ext_vector_type(4)));
typedef float  f32x4  __attribute__((ext_vector_type(4)));

// Problem shape (fixed by setup_inputs)
constexpr int Bb  = 4;
constexpr int L   = 4096;
constexpr int Dm  = 2048;
constexpr int S   = 512;
constexpr int KC  = 4;
constexpr int M   = Bb * L;        // 16384
constexpr int NP  = 2 * S + 1;     // 1025
constexpr int NP_PAD = 1152;       // 9 * 128 (zero-padded B rows for GEMM1)
constexpr int CL  = 128;
constexpr int NCH = L / CL;        // 32

// ---------------------------------------------------------------------------
// float -> bf16 (RNE), with zero-fill past in_elems (for padded weight buffers)
// ---------------------------------------------------------------------------
__global__ __launch_bounds__(256)
void f2b_kernel(const float* __restrict__ in, bf16_t* __restrict__ out,
                long out8, long in_elems)
{
    long i = (long)blockIdx.x * 256 + threadIdx.x;
    if (i >= out8) return;
    long e = i * 8;
    bf16x8 o;
    if (e + 8 <= in_elems) {
        float4 v0 = *(const float4*)(in + e);
        float4 v1 = *(const float4*)(in + e + 4);
        o[0] = (bf16_t)v0.x; o[1] = (bf16_t)v0.y;
        o[2] = (bf16_t)v0.z; o[3] = (bf16_t)v0.w;
        o[4] = (bf16_t)v1.x; o[5] = (bf16_t)v1.y;
        o[6] = (bf16_t)v1.z; o[7] = (bf16_t)v1.w;
    } else {
        #pragma unroll
        for (int k = 0; k < 8; ++k)
            o[k] = (e + k < in_elems) ? (bf16_t)in[e + k] : (bf16_t)0.f;
    }
    *(bf16x8*)(out + e) = o;
}

// ---------------------------------------------------------------------------
// causal depthwise conv -> fp32 (into d_out, used as scratch) + bf16 copy
// ---------------------------------------------------------------------------
__global__ __launch_bounds__(256)
void conv_kernel(const float* __restrict__ x, const float* __restrict__ w,
                 const float* __restrict__ bias, float* __restrict__ xc,
                 bf16_t* __restrict__ xcb)
{
    const int total4 = M * (Dm / 4);
    const float4* x4 = (const float4*)x;
    float4* xc4 = (float4*)xc;
    for (int i = blockIdx.x * blockDim.x + threadIdx.x; i < total4;
         i += gridDim.x * blockDim.x) {
        int d4 = i & (Dm / 4 - 1);
        int m  = i >> 9;
        int l  = m & (L - 1);
        int d  = d4 * 4;
        float w0[4], w1[4], w2[4], w3[4];
        *(float4*)w0 = *(const float4*)&w[(d + 0) * 4];
        *(float4*)w1 = *(const float4*)&w[(d + 1) * 4];
        *(float4*)w2 = *(const float4*)&w[(d + 2) * 4];
        *(float4*)w3 = *(const float4*)&w[(d + 3) * 4];
        float4 acc;
        acc.x = bias[d + 0]; acc.y = bias[d + 1];
        acc.z = bias[d + 2]; acc.w = bias[d + 3];
        #pragma unroll
        for (int k = 0; k < KC; ++k) {
            int lp = l - (KC - 1) + k;
            if (lp >= 0) {
                float4 xv = x4[(size_t)(m - (KC - 1) + k) * (Dm / 4) + d4];
                acc.x = fmaf(xv.x, w0[k], acc.x);
                acc.y = fmaf(xv.y, w1[k], acc.y);
                acc.z = fmaf(xv.z, w2[k], acc.z);
                acc.w = fmaf(xv.w, w3[k], acc.w);
            }
        }
        xc4[i] = acc;
        bf16x4 ob;
        ob[0] = (bf16_t)acc.x; ob[1] = (bf16_t)acc.y;
        ob[2] = (bf16_t)acc.z; ob[3] = (bf16_t)acc.w;
        *(bf16x4*)(xcb + (size_t)i * 4) = ob;
    }
}

// ---------------------------------------------------------------------------
// delta[m] = softplus(dcol[m])   (dcol = fp32 proj col 2S from GEMM1 epilogue)
// ---------------------------------------------------------------------------
__global__ __launch_bounds__(256)
void delta_kernel(const float* __restrict__ dcol, float* __restrict__ delta)
{
    int i = blockIdx.x * 256 + threadIdx.x;
    if (i < M) {
        float z = dcol[i];
        delta[i] = (z > 20.f) ? z : log1pf(__expf(z));
    }
}

// ---------------------------------------------------------------------------
// bf16 MFMA GEMM, m97 structure: 128x128 tile, BK=32, global_load_lds(16B),
// 4 waves 2x2, each 64x64 = 4x4 frags of v_mfma_f32_16x16x32_bf16.
// A [M][K] bf16, B [N][K] bf16 (i.e. B^T, K contiguous).
// EPI 0: params: store bf16 to Cb[m*NP+n] (n<NP), fp32 col 2S to dcol
// EPI 1: Bu:     Cf[m*N+n] = e0[m] * bf2f(eb[m*NP+n]) * acc
// EPI 2: out:    Cf[m*N+n] = acc + e0[n] * e1f[m*N+n]   (e1f == Cf, in-place)
// ---------------------------------------------------------------------------
template <int EPI>
__global__ __launch_bounds__(256)
void gemm_bf16(const bf16_t* __restrict__ A, const bf16_t* __restrict__ B,
               int N, int K,
               bf16_t* __restrict__ Cb, float* Cf, float* __restrict__ dcol,
               const float* __restrict__ e0, const bf16_t* __restrict__ eb,
               const float* e1f)
{
    __shared__ bf16_t As[128 * 32];
    __shared__ bf16_t Bs[128 * 32];

    const int tid  = threadIdx.x;
    const int lane = tid & 63;
    const int w    = tid >> 6;       // wave 0..3
    const int wm   = w >> 1, wn = w & 1;
    const int quad = lane >> 4, r = lane & 15;
    const int row0 = blockIdx.x * 128;
    const int col0 = blockIdx.y * 128;

    const int srow = tid >> 2;            // 0..63
    const int scol = (tid & 3) * 8;       // 0,8,16,24

    f32x4 acc[4][4];
    #pragma unroll
    for (int i = 0; i < 4; ++i)
        #pragma unroll
        for (int j = 0; j < 4; ++j) acc[i][j] = (f32x4){0.f, 0.f, 0.f, 0.f};

    for (int k0 = 0; k0 < K; k0 += 32) {
        if (k0) __syncthreads();     // prior compute done before overwrite
        #pragma unroll
        for (int it = 0; it < 2; ++it) {
            const bf16_t* sa = A + (size_t)(row0 + srow + it * 64) * K + k0 + scol;
            const bf16_t* sb = B + (size_t)(col0 + srow + it * 64) * K + k0 + scol;
            __builtin_amdgcn_global_load_lds(
                (__attribute__((address_space(1))) void*)sa,
                (__attribute__((address_space(3))) void*)(As + w * 512 + it * 2048),
                16, 0, 0);
            __builtin_amdgcn_global_load_lds(
                (__attribute__((address_space(1))) void*)sb,
                (__attribute__((address_space(3))) void*)(Bs + w * 512 + it * 2048),
                16, 0, 0);
        }
        __syncthreads();             // vmcnt drained by compiler before barrier

        bf16x8 af[4], bfr[4];
        #pragma unroll
        for (int i = 0; i < 4; ++i) {
            af[i]  = *(const bf16x8*)(As + (wm * 64 + i * 16 + r) * 32 + quad * 8);
            bfr[i] = *(const bf16x8*)(Bs + (wn * 64 + i * 16 + r) * 32 + quad * 8);
        }
        #pragma unroll
        for (int i = 0; i < 4; ++i)
            #pragma unroll
            for (int j = 0; j < 4; ++j)
                acc[i][j] = __builtin_amdgcn_mfma_f32_16x16x32_bf16(
                    af[i], bfr[j], acc[i][j], 0, 0, 0);
    }

    // epilogue: D mapping col=lane&15, row=(lane>>4)*4+reg  [m89-verified]
    #pragma unroll
    for (int i = 0; i < 4; ++i) {
        #pragma unroll
        for (int j = 0; j < 4; ++j) {
            #pragma unroll
            for (int g = 0; g < 4; ++g) {
                int mr = row0 + wm * 64 + i * 16 + quad * 4 + g;
                int nc = col0 + wn * 64 + j * 16 + r;
                float v = acc[i][j][g];
                if (EPI == 0) {
                    if (nc < NP) Cb[(size_t)mr * NP + nc] = (bf16_t)v;
                    if (nc == 2 * S) dcol[mr] = v;
                } else if (EPI == 1) {
                    float Bm = (float)eb[(size_t)mr * NP + nc];
                    Cf[(size_t)mr * N + nc] = e0[mr] * Bm * v;
                } else {
                    float xc = e1f[(size_t)mr * N + nc];
                    Cf[(size_t)mr * N + nc] = v + e0[nc] * xc;
                }
            }
        }
    }
}

// ---------------------------------------------------------------------------
// chunked scan: h[l] = a[l]*h[l-1] + u[l],  a = exp(-exp(A_log[s]) * delta[l])
// ---------------------------------------------------------------------------
__global__ __launch_bounds__(256)
void scan_pass1(const float* __restrict__ Bu, const float* __restrict__ delta,
                const float* __restrict__ A_log,
                float* __restrict__ cP, float* __restrict__ cH)
{
    int s = blockIdx.x * 256 + threadIdx.x;
    int c = blockIdx.y;
    int b = blockIdx.z;
    float Acoef = -expf(A_log[s]);
    float P = 1.f, h = 0.f;
    int mbase = b * L + c * CL;
    for (int t = 0; t < CL; ++t) {
        float a = __expf(Acoef * delta[mbase + t]);
        float u = Bu[(size_t)(mbase + t) * S + s];
        h = fmaf(a, h, u);
        P *= a;
    }
    int id = b * S + s;
    cP[(size_t)id * NCH + c] = P;
    cH[(size_t)id * NCH + c] = h;
}

__global__ __launch_bounds__(256)
void scan_pass2(const float* __restrict__ cP, const float* __restrict__ cH,
                float* __restrict__ init)
{
    int id = blockIdx.x * 256 + threadIdx.x;
    if (id < Bb * S) {
        float h = 0.f;
        for (int c = 0; c < NCH; ++c) {
            init[(size_t)id * NCH + c] = h;
            h = fmaf(cP[(size_t)id * NCH + c], h, cH[(size_t)id * NCH + c]);
        }
    }
}

__global__ __launch_bounds__(256)
void scan_pass3(const float* __restrict__ Bu, const float* __restrict__ delta,
                const bf16_t* __restrict__ params_bf,
                const float* __restrict__ A_log,
                const float* __restrict__ init, bf16_t* __restrict__ hmod)
{
    int s = blockIdx.x * 256 + threadIdx.x;
    int c = blockIdx.y;
    int b = blockIdx.z;
    float Acoef = -expf(A_log[s]);
    float h = init[(size_t)(b * S + s) * NCH + c];
    int mbase = b * L + c * CL;
    for (int t = 0; t < CL; ++t) {
        int m = mbase + t;
        float a = __expf(Acoef * delta[m]);
        float u = Bu[(size_t)m * S + s];
        h = fmaf(a, h, u);
        float Cm = (float)params_bf[(size_t)m * NP + S + s];
        hmod[(size_t)m * S + s] = (bf16_t)(Cm * h);
    }
}

// ---------------------------------------------------------------------------
extern "C" void kernel_launch(void* const* d_in, const int* in_sizes, int n_in,
                              void* d_out, int out_size, void* d_ws, size_t ws_size,
                              hipStream_t stream)
{
    const float* x        = (const float*)d_in[0];
    const float* Wxproj   = (const float*)d_in[1];
    const float* Winproj  = (const float*)d_in[2];
    const float* Woutproj = (const float*)d_in[3];
    const float* conv_w   = (const float*)d_in[4];
    const float* conv_b   = (const float*)d_in[5];
    const float* A_log    = (const float*)d_in[6];
    const float* Dvec     = (const float*)d_in[7];
    float* out = (float*)d_out;

    // fp32 workspace
    float* ws_Bu    = (float*)d_ws;                       // M*S
    float* ws_dcol  = ws_Bu + (size_t)M * S;              // M
    float* ws_delta = ws_dcol + M;                        // M
    float* ws_cP    = ws_delta + M;                       // Bb*S*NCH
    float* ws_cH    = ws_cP + (size_t)Bb * S * NCH;
    float* ws_init  = ws_cH + (size_t)Bb * S * NCH;
    // bf16 workspace
    bf16_t* params_bf = (bf16_t*)(ws_init + (size_t)Bb * S * NCH); // M*NP
    bf16_t* x_bf      = params_bf + (size_t)M * NP;       // M*Dm
    bf16_t* hmod_bf   = x_bf;                             // M*S (alias, x_bf dead)
    bf16_t* xconv_bf  = x_bf + (size_t)M * Dm;            // M*Dm
    bf16_t* Wx_bf     = xconv_bf + (size_t)M * Dm;        // NP_PAD*Dm
    bf16_t* Win_bf    = Wx_bf + (size_t)NP_PAD * Dm;      // S*Dm
    bf16_t* Wout_bf   = Win_bf + (size_t)S * Dm;          // Dm*S
    float*  xconv_f   = out;                              // M*Dm fp32 scratch in d_out

    // 1. bf16 conversions
    long x8 = (long)M * Dm / 8;
    f2b_kernel<<<(x8 + 255) / 256, 256, 0, stream>>>(x, x_bf, x8, (long)M * Dm);
    long wx8 = (long)NP_PAD * Dm / 8;
    f2b_kernel<<<(wx8 + 255) / 256, 256, 0, stream>>>(Wxproj, Wx_bf, wx8, (long)NP * Dm);
    long wi8 = (long)S * Dm / 8;
    f2b_kernel<<<(wi8 + 255) / 256, 256, 0, stream>>>(Winproj, Win_bf, wi8, (long)S * Dm);
    f2b_kernel<<<(wi8 + 255) / 256, 256, 0, stream>>>(Woutproj, Wout_bf, wi8, (long)Dm * S);

    // 2. depthwise causal conv -> xconv fp32 (in d_out) + bf16
    conv_kernel<<<2048, 256, 0, stream>>>(x, conv_w, conv_b, xconv_f, xconv_bf);

    // 3. GEMM1: ssm_params(bf16) = x @ Wxproj^T ; fp32 delta col
    dim3 g1(M / 128, NP_PAD / 128);
    gemm_bf16<0><<<g1, 256, 0, stream>>>(x_bf, Wx_bf, NP, Dm,
                                         params_bf, nullptr, ws_dcol,
                                         nullptr, nullptr, nullptr);

    // 4. delta = softplus(dcol)
    delta_kernel<<<M / 256, 256, 0, stream>>>(ws_dcol, ws_delta);

    // 5. GEMM2: Bu = delta * Bmat * (x_conv @ Winproj^T)
    dim3 g2(M / 128, S / 128);
    gemm_bf16<1><<<g2, 256, 0, stream>>>(xconv_bf, Win_bf, S, Dm,
                                         nullptr, ws_Bu, nullptr,
                                         ws_delta, params_bf, nullptr);

    // 6. chunked scan; h_mod = Cmat*h -> bf16
    dim3 gs(S / 256, NCH, Bb);
    scan_pass1<<<gs, 256, 0, stream>>>(ws_Bu, ws_delta, A_log, ws_cP, ws_cH);
    scan_pass2<<<(Bb * S) / 256, 256, 0, stream>>>(ws_cP, ws_cH, ws_init);
    scan_pass3<<<gs, 256, 0, stream>>>(ws_Bu, ws_delta, params_bf, A_log,
                                       ws_init, hmod_bf);

    // 7. GEMM3: out = h_mod @ Woutproj^T + D * x_conv   (in-place over d_out)
    dim3 g3(M / 128, Dm / 128);
    gemm_bf16<2><<<g3, 256, 0, stream>>>(hmod_bf, Wout_bf, Dm, S,
                                         nullptr, out, nullptr,
                                         Dvec, nullptr, (const float*)out);
}

// Round 4
// 424.109 us; speedup vs baseline: 4.9709x; 1.3041x over previous
//
#include <hip/hip_runtime.h>
#include <math.h>

typedef __bf16 bf16_t;
typedef __bf16 bf16x8 __attribute__((ext_vector_type(8)));
typedef __bf16 bf16x4 __attribute__((ext_vector_type(4)));
typedef float  f32x4  __attribute__((ext_vector_type(4)));

// Problem shape (fixed by setup_inputs)
constexpr int Bb  = 4;
constexpr int L   = 4096;
constexpr int Dm  = 2048;
constexpr int S   = 512;
constexpr int M   = Bb * L;        // 16384
constexpr int NP  = 2 * S + 1;     // 1025
constexpr int NP_PAD = 1152;       // 9 * 128 (zero-padded B rows for GEMM1)
constexpr int CL  = 128;           // scan chunk length
constexpr int NCH = L / CL;        // 32
constexpr int TL  = 32;            // conv time-chunk per thread
constexpr int NTC = L / TL;        // 128

// ---------------------------------------------------------------------------
// float -> bf16 (RNE), zero-fill past in_elems (for padded weight buffers)
// ---------------------------------------------------------------------------
__global__ __launch_bounds__(256)
void f2b_kernel(const float* __restrict__ in, bf16_t* __restrict__ out,
                long out8, long in_elems)
{
    long i = (long)blockIdx.x * 256 + threadIdx.x;
    if (i >= out8) return;
    long e = i * 8;
    bf16x8 o;
    if (e + 8 <= in_elems) {
        float4 v0 = *(const float4*)(in + e);
        float4 v1 = *(const float4*)(in + e + 4);
        o[0] = (bf16_t)v0.x; o[1] = (bf16_t)v0.y;
        o[2] = (bf16_t)v0.z; o[3] = (bf16_t)v0.w;
        o[4] = (bf16_t)v1.x; o[5] = (bf16_t)v1.y;
        o[6] = (bf16_t)v1.z; o[7] = (bf16_t)v1.w;
    } else {
        #pragma unroll
        for (int k = 0; k < 8; ++k)
            o[k] = (e + k < in_elems) ? (bf16_t)in[e + k] : (bf16_t)0.f;
    }
    *(bf16x8*)(out + e) = o;
}

// ---------------------------------------------------------------------------
// Fused causal depthwise conv + x->bf16. Sliding window: each thread owns
// (b, d4, 32-step L-chunk), carries 3 prior rows in registers -> each x
// element fetched once (9% halo). Emits xconv bf16 AND x bf16 (f2b fused).
// ---------------------------------------------------------------------------
__global__ __launch_bounds__(256)
void conv_fused_kernel(const float* __restrict__ x, const float* __restrict__ w,
                       const float* __restrict__ bias,
                       bf16_t* __restrict__ xcb, bf16_t* __restrict__ xb)
{
    const float4* x4 = (const float4*)x;
    int g   = blockIdx.x * 256 + threadIdx.x;   // 0 .. Bb*NTC*512-1
    int d4  = g & 511;
    int rest = g >> 9;
    int c   = rest & (NTC - 1);
    int b   = rest >> 7;
    int d   = d4 * 4;

    // per-channel taps: wj[k] = w[(d+j)*4 + k]
    float w0[4], w1[4], w2[4], w3[4];
    *(float4*)w0 = *(const float4*)&w[(d + 0) * 4];
    *(float4*)w1 = *(const float4*)&w[(d + 1) * 4];
    *(float4*)w2 = *(const float4*)&w[(d + 2) * 4];
    *(float4*)w3 = *(const float4*)&w[(d + 3) * 4];
    float4 bs = *(const float4*)&bias[d];

    const int l0 = c * TL;
    const size_t rowbase = (size_t)b * L;

    // preload window rows l0-3, l0-2, l0-1
    float4 win[3];
    #pragma unroll
    for (int i = 0; i < 3; ++i) {
        int lp = l0 - 3 + i;
        win[i] = (lp >= 0) ? x4[(rowbase + lp) * 512 + d4]
                           : make_float4(0.f, 0.f, 0.f, 0.f);
    }

    #pragma unroll
    for (int t = 0; t < TL; ++t) {
        size_t ri = (rowbase + l0 + t) * 512 + d4;
        float4 cur = x4[ri];
        float4 acc = bs;
        acc.x = fmaf(win[0].x, w0[0], acc.x);
        acc.y = fmaf(win[0].y, w1[0], acc.y);
        acc.z = fmaf(win[0].z, w2[0], acc.z);
        acc.w = fmaf(win[0].w, w3[0], acc.w);
        acc.x = fmaf(win[1].x, w0[1], acc.x);
        acc.y = fmaf(win[1].y, w1[1], acc.y);
        acc.z = fmaf(win[1].z, w2[1], acc.z);
        acc.w = fmaf(win[1].w, w3[1], acc.w);
        acc.x = fmaf(win[2].x, w0[2], acc.x);
        acc.y = fmaf(win[2].y, w1[2], acc.y);
        acc.z = fmaf(win[2].z, w2[2], acc.z);
        acc.w = fmaf(win[2].w, w3[2], acc.w);
        acc.x = fmaf(cur.x, w0[3], acc.x);
        acc.y = fmaf(cur.y, w1[3], acc.y);
        acc.z = fmaf(cur.z, w2[3], acc.z);
        acc.w = fmaf(cur.w, w3[3], acc.w);

        bf16x4 oc, ox;
        oc[0] = (bf16_t)acc.x; oc[1] = (bf16_t)acc.y;
        oc[2] = (bf16_t)acc.z; oc[3] = (bf16_t)acc.w;
        ox[0] = (bf16_t)cur.x; ox[1] = (bf16_t)cur.y;
        ox[2] = (bf16_t)cur.z; ox[3] = (bf16_t)cur.w;
        *(bf16x4*)(xcb + ri * 4) = oc;
        *(bf16x4*)(xb  + ri * 4) = ox;

        win[0] = win[1]; win[1] = win[2]; win[2] = cur;
    }
}

// ---------------------------------------------------------------------------
// delta[m] = softplus(dcol[m])
// ---------------------------------------------------------------------------
__global__ __launch_bounds__(256)
void delta_kernel(const float* __restrict__ dcol, float* __restrict__ delta)
{
    int i = blockIdx.x * 256 + threadIdx.x;
    if (i < M) {
        float z = dcol[i];
        delta[i] = (z > 20.f) ? z : log1pf(__expf(z));
    }
}

// ---------------------------------------------------------------------------
// bf16 MFMA GEMM, m97 structure: 128x128 tile, BK=32, global_load_lds(16B),
// 4 waves 2x2, each 64x64 = 4x4 frags of v_mfma_f32_16x16x32_bf16.
// A [M][K] bf16, B [N][K] bf16 (B^T, K contiguous).
// EPI 0: params: store bf16 Cb[m*NP+n] (n<NP), fp32 col 2S to dcol
// EPI 1: Bu:     Cf[m*N+n] = e0[m] * bf2f(eb[m*NP+n]) * acc
// EPI 2: out:    Cf[m*N+n] = acc + e0[n] * bf2f(eb[m*N+n])   (eb = xconv_bf)
// ---------------------------------------------------------------------------
template <int EPI>
__global__ __launch_bounds__(256)
void gemm_bf16(const bf16_t* __restrict__ A, const bf16_t* __restrict__ B,
               int N, int K,
               bf16_t* __restrict__ Cb, float* __restrict__ Cf,
               float* __restrict__ dcol,
               const float* __restrict__ e0, const bf16_t* __restrict__ eb)
{
    __shared__ bf16_t As[128 * 32];
    __shared__ bf16_t Bs[128 * 32];

    const int tid  = threadIdx.x;
    const int lane = tid & 63;
    const int w    = tid >> 6;
    const int wm   = w >> 1, wn = w & 1;
    const int quad = lane >> 4, r = lane & 15;
    const int row0 = blockIdx.x * 128;
    const int col0 = blockIdx.y * 128;

    const int srow = tid >> 2;
    const int scol = (tid & 3) * 8;

    f32x4 acc[4][4];
    #pragma unroll
    for (int i = 0; i < 4; ++i)
        #pragma unroll
        for (int j = 0; j < 4; ++j) acc[i][j] = (f32x4){0.f, 0.f, 0.f, 0.f};

    for (int k0 = 0; k0 < K; k0 += 32) {
        if (k0) __syncthreads();
        #pragma unroll
        for (int it = 0; it < 2; ++it) {
            const bf16_t* sa = A + (size_t)(row0 + srow + it * 64) * K + k0 + scol;
            const bf16_t* sb = B + (size_t)(col0 + srow + it * 64) * K + k0 + scol;
            __builtin_amdgcn_global_load_lds(
                (__attribute__((address_space(1))) void*)sa,
                (__attribute__((address_space(3))) void*)(As + w * 512 + it * 2048),
                16, 0, 0);
            __builtin_amdgcn_global_load_lds(
                (__attribute__((address_space(1))) void*)sb,
                (__attribute__((address_space(3))) void*)(Bs + w * 512 + it * 2048),
                16, 0, 0);
        }
        __syncthreads();

        bf16x8 af[4], bfr[4];
        #pragma unroll
        for (int i = 0; i < 4; ++i) {
            af[i]  = *(const bf16x8*)(As + (wm * 64 + i * 16 + r) * 32 + quad * 8);
            bfr[i] = *(const bf16x8*)(Bs + (wn * 64 + i * 16 + r) * 32 + quad * 8);
        }
        #pragma unroll
        for (int i = 0; i < 4; ++i)
            #pragma unroll
            for (int j = 0; j < 4; ++j)
                acc[i][j] = __builtin_amdgcn_mfma_f32_16x16x32_bf16(
                    af[i], bfr[j], acc[i][j], 0, 0, 0);
    }

    // epilogue: D mapping col=lane&15, row=(lane>>4)*4+reg  [m89-verified]
    #pragma unroll
    for (int i = 0; i < 4; ++i) {
        #pragma unroll
        for (int j = 0; j < 4; ++j) {
            #pragma unroll
            for (int g = 0; g < 4; ++g) {
                int mr = row0 + wm * 64 + i * 16 + quad * 4 + g;
                int nc = col0 + wn * 64 + j * 16 + r;
                float v = acc[i][j][g];
                if (EPI == 0) {
                    if (nc < NP) Cb[(size_t)mr * NP + nc] = (bf16_t)v;
                    if (nc == 2 * S) dcol[mr] = v;
                } else if (EPI == 1) {
                    float Bm = (float)eb[(size_t)mr * NP + nc];
                    Cf[(size_t)mr * N + nc] = e0[mr] * Bm * v;
                } else {
                    float xc = (float)eb[(size_t)mr * N + nc];
                    Cf[(size_t)mr * N + nc] = v + e0[nc] * xc;
                }
            }
        }
    }
}

// ---------------------------------------------------------------------------
// chunked scan: h[l] = a[l]*h[l-1] + u[l],  a = exp(-exp(A_log[s]) * delta[l])
// ---------------------------------------------------------------------------
__global__ __launch_bounds__(256)
void scan_pass1(const float* __restrict__ Bu, const float* __restrict__ delta,
                const float* __restrict__ A_log,
                float* __restrict__ cP, float* __restrict__ cH)
{
    int s = blockIdx.x * 256 + threadIdx.x;
    int c = blockIdx.y;
    int b = blockIdx.z;
    float Acoef = -expf(A_log[s]);
    float P = 1.f, h = 0.f;
    int mbase = b * L + c * CL;
    for (int t = 0; t < CL; ++t) {
        float a = __expf(Acoef * delta[mbase + t]);
        float u = Bu[(size_t)(mbase + t) * S + s];
        h = fmaf(a, h, u);
        P *= a;
    }
    int id = b * S + s;
    cP[(size_t)id * NCH + c] = P;
    cH[(size_t)id * NCH + c] = h;
}

__global__ __launch_bounds__(256)
void scan_pass2(const float* __restrict__ cP, const float* __restrict__ cH,
                float* __restrict__ init)
{
    int id = blockIdx.x * 256 + threadIdx.x;
    if (id < Bb * S) {
        float h = 0.f;
        for (int c = 0; c < NCH; ++c) {
            init[(size_t)id * NCH + c] = h;
            h = fmaf(cP[(size_t)id * NCH + c], h, cH[(size_t)id * NCH + c]);
        }
    }
}

__global__ __launch_bounds__(256)
void scan_pass3(const float* __restrict__ Bu, const float* __restrict__ delta,
                const bf16_t* __restrict__ params_bf,
                const float* __restrict__ A_log,
                const float* __restrict__ init, bf16_t* __restrict__ hmod)
{
    int s = blockIdx.x * 256 + threadIdx.x;
    int c = blockIdx.y;
    int b = blockIdx.z;
    float Acoef = -expf(A_log[s]);
    float h = init[(size_t)(b * S + s) * NCH + c];
    int mbase = b * L + c * CL;
    for (int t = 0; t < CL; ++t) {
        int m = mbase + t;
        float a = __expf(Acoef * delta[m]);
        float u = Bu[(size_t)m * S + s];
        h = fmaf(a, h, u);
        float Cm = (float)params_bf[(size_t)m * NP + S + s];
        hmod[(size_t)m * S + s] = (bf16_t)(Cm * h);
    }
}

// ---------------------------------------------------------------------------
extern "C" void kernel_launch(void* const* d_in, const int* in_sizes, int n_in,
                              void* d_out, int out_size, void* d_ws, size_t ws_size,
                              hipStream_t stream)
{
    const float* x        = (const float*)d_in[0];
    const float* Wxproj   = (const float*)d_in[1];
    const float* Winproj  = (const float*)d_in[2];
    const float* Woutproj = (const float*)d_in[3];
    const float* conv_w   = (const float*)d_in[4];
    const float* conv_b   = (const float*)d_in[5];
    const float* A_log    = (const float*)d_in[6];
    const float* Dvec     = (const float*)d_in[7];
    float* out = (float*)d_out;

    // fp32 workspace
    float* ws_Bu    = (float*)d_ws;                       // M*S
    float* ws_dcol  = ws_Bu + (size_t)M * S;              // M
    float* ws_delta = ws_dcol + M;                        // M
    float* ws_cP    = ws_delta + M;                       // Bb*S*NCH
    float* ws_cH    = ws_cP + (size_t)Bb * S * NCH;
    float* ws_init  = ws_cH + (size_t)Bb * S * NCH;
    // bf16 workspace
    bf16_t* params_bf = (bf16_t*)(ws_init + (size_t)Bb * S * NCH); // M*NP
    bf16_t* x_bf      = params_bf + (size_t)M * NP;       // M*Dm
    bf16_t* hmod_bf   = x_bf;                             // M*S (alias, x_bf dead)
    bf16_t* xconv_bf  = x_bf + (size_t)M * Dm;            // M*Dm
    bf16_t* Wx_bf     = xconv_bf + (size_t)M * Dm;        // NP_PAD*Dm
    bf16_t* Win_bf    = Wx_bf + (size_t)NP_PAD * Dm;      // S*Dm
    bf16_t* Wout_bf   = Win_bf + (size_t)S * Dm;          // Dm*S

    // 1. weight bf16 conversions (x handled by fused conv)
    long wx8 = (long)NP_PAD * Dm / 8;
    f2b_kernel<<<(wx8 + 255) / 256, 256, 0, stream>>>(Wxproj, Wx_bf, wx8, (long)NP * Dm);
    long wi8 = (long)S * Dm / 8;
    f2b_kernel<<<(wi8 + 255) / 256, 256, 0, stream>>>(Winproj, Win_bf, wi8, (long)S * Dm);
    f2b_kernel<<<(wi8 + 255) / 256, 256, 0, stream>>>(Woutproj, Wout_bf, wi8, (long)Dm * S);

    // 2. fused conv: x -> xconv_bf + x_bf  (each x element fetched once)
    conv_fused_kernel<<<(Bb * NTC * 512) / 256, 256, 0, stream>>>(
        x, conv_w, conv_b, xconv_bf, x_bf);

    // 3. GEMM1: ssm_params(bf16) = x @ Wxproj^T ; fp32 delta col
    dim3 g1(M / 128, NP_PAD / 128);
    gemm_bf16<0><<<g1, 256, 0, stream>>>(x_bf, Wx_bf, NP, Dm,
                                         params_bf, nullptr, ws_dcol,
                                         nullptr, nullptr);

    // 4. delta = softplus(dcol)
    delta_kernel<<<M / 256, 256, 0, stream>>>(ws_dcol, ws_delta);

    // 5. GEMM2: Bu = delta * Bmat * (x_conv @ Winproj^T)
    dim3 g2(M / 128, S / 128);
    gemm_bf16<1><<<g2, 256, 0, stream>>>(xconv_bf, Win_bf, S, Dm,
                                         nullptr, ws_Bu, nullptr,
                                         ws_delta, params_bf);

    // 6. chunked scan; h_mod = Cmat*h -> bf16
    dim3 gs(S / 256, NCH, Bb);
    scan_pass1<<<gs, 256, 0, stream>>>(ws_Bu, ws_delta, A_log, ws_cP, ws_cH);
    scan_pass2<<<(Bb * S) / 256, 256, 0, stream>>>(ws_cP, ws_cH, ws_init);
    scan_pass3<<<gs, 256, 0, stream>>>(ws_Bu, ws_delta, params_bf, A_log,
                                       ws_init, hmod_bf);

    // 7. GEMM3: out = h_mod @ Woutproj^T + D * x_conv
    dim3 g3(M / 128, Dm / 128);
    gemm_bf16<2><<<g3, 256, 0, stream>>>(hmod_bf, Wout_bf, Dm, S,
                                         nullptr, out, nullptr,
                                         Dvec, xconv_bf);
}

// Round 5
// 329.681 us; speedup vs baseline: 6.3947x; 1.2864x over previous
//
#include <hip/hip_runtime.h>
#include <math.h>

typedef __bf16 bf16_t;
typedef __bf16 bf16x8 __attribute__((ext_vector_type(8)));
typedef __bf16 bf16x4 __attribute__((ext_vector_type(4)));
typedef float  f32x4  __attribute__((ext_vector_type(4)));

// Problem shape (fixed by setup_inputs)
constexpr int Bb  = 4;
constexpr int L   = 4096;
constexpr int Dm  = 2048;
constexpr int S   = 512;
constexpr int M   = Bb * L;        // 16384
constexpr int NP  = 2 * S + 1;     // 1025
constexpr int NP_PAD = 1280;       // 5 * 256 (zero-padded B rows for GEMM1)
constexpr int CL  = 128;           // scan chunk length
constexpr int NCH = L / CL;        // 32
constexpr int TL  = 32;            // conv time-chunk per thread
constexpr int NTC = L / TL;        // 128

#define AS1 __attribute__((address_space(1)))
#define AS3 __attribute__((address_space(3)))

// ---------------------------------------------------------------------------
// float -> bf16 (RNE), zero-fill past in_elems (for padded weight buffers)
// ---------------------------------------------------------------------------
__global__ __launch_bounds__(256)
void f2b_kernel(const float* __restrict__ in, bf16_t* __restrict__ out,
                long out8, long in_elems)
{
    long i = (long)blockIdx.x * 256 + threadIdx.x;
    if (i >= out8) return;
    long e = i * 8;
    bf16x8 o;
    if (e + 8 <= in_elems) {
        float4 v0 = *(const float4*)(in + e);
        float4 v1 = *(const float4*)(in + e + 4);
        o[0] = (bf16_t)v0.x; o[1] = (bf16_t)v0.y;
        o[2] = (bf16_t)v0.z; o[3] = (bf16_t)v0.w;
        o[4] = (bf16_t)v1.x; o[5] = (bf16_t)v1.y;
        o[6] = (bf16_t)v1.z; o[7] = (bf16_t)v1.w;
    } else {
        #pragma unroll
        for (int k = 0; k < 8; ++k)
            o[k] = (e + k < in_elems) ? (bf16_t)in[e + k] : (bf16_t)0.f;
    }
    *(bf16x8*)(out + e) = o;
}

// ---------------------------------------------------------------------------
// Fused causal depthwise conv + x->bf16 (sliding window, x fetched once)
// ---------------------------------------------------------------------------
__global__ __launch_bounds__(256)
void conv_fused_kernel(const float* __restrict__ x, const float* __restrict__ w,
                       const float* __restrict__ bias,
                       bf16_t* __restrict__ xcb, bf16_t* __restrict__ xb)
{
    const float4* x4 = (const float4*)x;
    int g   = blockIdx.x * 256 + threadIdx.x;
    int d4  = g & 511;
    int rest = g >> 9;
    int c   = rest & (NTC - 1);
    int b   = rest >> 7;
    int d   = d4 * 4;

    float w0[4], w1[4], w2[4], w3[4];
    *(float4*)w0 = *(const float4*)&w[(d + 0) * 4];
    *(float4*)w1 = *(const float4*)&w[(d + 1) * 4];
    *(float4*)w2 = *(const float4*)&w[(d + 2) * 4];
    *(float4*)w3 = *(const float4*)&w[(d + 3) * 4];
    float4 bs = *(const float4*)&bias[d];

    const int l0 = c * TL;
    const size_t rowbase = (size_t)b * L;

    float4 win[3];
    #pragma unroll
    for (int i = 0; i < 3; ++i) {
        int lp = l0 - 3 + i;
        win[i] = (lp >= 0) ? x4[(rowbase + lp) * 512 + d4]
                           : make_float4(0.f, 0.f, 0.f, 0.f);
    }

    #pragma unroll
    for (int t = 0; t < TL; ++t) {
        size_t ri = (rowbase + l0 + t) * 512 + d4;
        float4 cur = x4[ri];
        float4 acc = bs;
        acc.x = fmaf(win[0].x, w0[0], acc.x);
        acc.y = fmaf(win[0].y, w1[0], acc.y);
        acc.z = fmaf(win[0].z, w2[0], acc.z);
        acc.w = fmaf(win[0].w, w3[0], acc.w);
        acc.x = fmaf(win[1].x, w0[1], acc.x);
        acc.y = fmaf(win[1].y, w1[1], acc.y);
        acc.z = fmaf(win[1].z, w2[1], acc.z);
        acc.w = fmaf(win[1].w, w3[1], acc.w);
        acc.x = fmaf(win[2].x, w0[2], acc.x);
        acc.y = fmaf(win[2].y, w1[2], acc.y);
        acc.z = fmaf(win[2].z, w2[2], acc.z);
        acc.w = fmaf(win[2].w, w3[2], acc.w);
        acc.x = fmaf(cur.x, w0[3], acc.x);
        acc.y = fmaf(cur.y, w1[3], acc.y);
        acc.z = fmaf(cur.z, w2[3], acc.z);
        acc.w = fmaf(cur.w, w3[3], acc.w);

        bf16x4 oc, ox;
        oc[0] = (bf16_t)acc.x; oc[1] = (bf16_t)acc.y;
        oc[2] = (bf16_t)acc.z; oc[3] = (bf16_t)acc.w;
        ox[0] = (bf16_t)cur.x; ox[1] = (bf16_t)cur.y;
        ox[2] = (bf16_t)cur.z; ox[3] = (bf16_t)cur.w;
        *(bf16x4*)(xcb + ri * 4) = oc;
        *(bf16x4*)(xb  + ri * 4) = ox;

        win[0] = win[1]; win[1] = win[2]; win[2] = cur;
    }
}

// ---------------------------------------------------------------------------
// delta[m] = softplus(dcol[m])
// ---------------------------------------------------------------------------
__global__ __launch_bounds__(256)
void delta_kernel(const float* __restrict__ dcol, float* __restrict__ delta)
{
    int i = blockIdx.x * 256 + threadIdx.x;
    if (i < M) {
        float z = dcol[i];
        delta[i] = (z > 20.f) ? z : log1pf(__expf(z));
    }
}

// ---------------------------------------------------------------------------
// 256x256 tile, BK=64, 8 waves (2x4), 4-phase counted-vmcnt schedule.
// LDS 128KB dynamic: [A0:0, B0:16384, A1:32768, B1:49152] (elems), each
// region 256 rows x 64 cols bf16, row-major, XOR-swizzled:
//   element (R,k) stored at R*64 + (k ^ ((R&7)<<3)).
// global_load_lds writes linearly -> global SOURCE is inverse-swizzled
// (same involution), ds_read applies the swizzle (rule #21).
// Slab staging order per tile: A0, B0, B1, A1 (consumption-ordered);
// quadrant order (mh,nh): (0,0),(0,1),(1,1),(1,0); every wait = vmcnt(4).
// ---------------------------------------------------------------------------
__device__ __forceinline__ void stage_slabA(const bf16_t* __restrict__ A,
    bf16_t* lds, int ldsbase, int row0, int K, int kcol, int mh,
    int wid, int lrow, int cswz)
{
    #pragma unroll
    for (int round = 0; round < 2; ++round) {
        int Rb = round * 128 + mh * 64 + wid * 8;
        const bf16_t* src = A + (size_t)(row0 + Rb + lrow) * K + kcol + cswz;
        __builtin_amdgcn_global_load_lds(
            (AS1 void*)src, (AS3 void*)(lds + ldsbase + Rb * 64), 16, 0, 0);
    }
}

__device__ __forceinline__ void stage_slabB(const bf16_t* __restrict__ B,
    bf16_t* lds, int ldsbase, int col0, int K, int kcol, int nh,
    int wid, int lrow, int cswz)
{
    #pragma unroll
    for (int round = 0; round < 2; ++round) {
        int c  = round * 8 + wid;
        int Rb = (c >> 2) * 64 + nh * 32 + (c & 3) * 8;
        const bf16_t* src = B + (size_t)(col0 + Rb + lrow) * K + kcol + cswz;
        __builtin_amdgcn_global_load_lds(
            (AS1 void*)src, (AS3 void*)(lds + ldsbase + Rb * 64), 16, 0, 0);
    }
}

template <int MH>
__device__ __forceinline__ void load_fragsA(const bf16_t* lds, int Abase,
    int wm, int r, int quad, bf16x8 (&af)[4][2])
{
    #pragma unroll
    for (int i4 = 0; i4 < 4; ++i4) {
        const int R = wm * 128 + (MH * 4 + i4) * 16 + r;
        #pragma unroll
        for (int ks = 0; ks < 2; ++ks)
            af[i4][ks] = *(const bf16x8*)(lds + Abase + R * 64 +
                           ((ks * 32 + quad * 8) ^ ((r & 7) << 3)));
    }
}

template <int NH>
__device__ __forceinline__ void load_fragsB(const bf16_t* lds, int Bbase,
    int wn, int r, int quad, bf16x8 (&bfr)[2][2])
{
    #pragma unroll
    for (int j2 = 0; j2 < 2; ++j2) {
        const int R = wn * 64 + (NH * 2 + j2) * 16 + r;
        #pragma unroll
        for (int ks = 0; ks < 2; ++ks)
            bfr[j2][ks] = *(const bf16x8*)(lds + Bbase + R * 64 +
                            ((ks * 32 + quad * 8) ^ ((r & 7) << 3)));
    }
}

template <int MH, int NH>
__device__ __forceinline__ void do_mfma(bf16x8 (&af)[4][2], bf16x8 (&bfr)[2][2],
                                        f32x4 (&acc)[8][4])
{
    __builtin_amdgcn_s_setprio(1);
    #pragma unroll
    for (int ks = 0; ks < 2; ++ks)
        #pragma unroll
        for (int i4 = 0; i4 < 4; ++i4)
            #pragma unroll
            for (int j2 = 0; j2 < 2; ++j2)
                acc[MH * 4 + i4][NH * 2 + j2] =
                    __builtin_amdgcn_mfma_f32_16x16x32_bf16(
                        af[i4][ks], bfr[j2][ks],
                        acc[MH * 4 + i4][NH * 2 + j2], 0, 0, 0);
    __builtin_amdgcn_s_setprio(0);
}

#define WAITBAR() do { \
    asm volatile("s_waitcnt vmcnt(4)" ::: "memory"); \
    __builtin_amdgcn_s_barrier(); } while (0)

// EPI 0: params: bf16 Cb[m*NP+n] (n<NP), fp32 col 2S -> dcol
// EPI 1: Bu:     Cf[m*N+n] = e0[m] * bf2f(eb[m*NP+n]) * acc
// EPI 2: out:    Cf[m*N+n] = acc + e0[n] * bf2f(eb[m*N+n])
template <int EPI>
__global__ __launch_bounds__(512, 2)
void gemm8p(const bf16_t* __restrict__ A, const bf16_t* __restrict__ B,
            int N, int K, int NT,
            bf16_t* __restrict__ Cb, float* __restrict__ Cf,
            float* __restrict__ dcol,
            const float* __restrict__ e0, const bf16_t* __restrict__ eb)
{
    extern __shared__ __align__(16) char smem_raw[];
    bf16_t* lds = (bf16_t*)smem_raw;

    const int tid  = threadIdx.x;
    const int lane = tid & 63;
    const int wid  = tid >> 6;       // 0..7
    const int wm   = wid >> 2;       // 0..1
    const int wn   = wid & 3;        // 0..3
    const int r    = lane & 15;
    const int quad = lane >> 4;
    const int row0 = blockIdx.x * 256;
    const int col0 = blockIdx.y * 256;
    const int lrow = lane >> 3;                  // 0..7
    const int cswz = 8 * ((lane & 7) ^ lrow);    // inverse-swizzled src col

    f32x4 acc[8][4];
    #pragma unroll
    for (int i = 0; i < 8; ++i)
        #pragma unroll
        for (int j = 0; j < 4; ++j) acc[i][j] = (f32x4){0.f, 0.f, 0.f, 0.f};

    // prologue: tile 0 -> buffer 0; order A0, B0, B1, A1
    stage_slabA(A, lds, 0,     row0, K, 0, 0, wid, lrow, cswz);
    stage_slabB(B, lds, 16384, col0, K, 0, 0, wid, lrow, cswz);
    stage_slabB(B, lds, 16384, col0, K, 0, 1, wid, lrow, cswz);
    stage_slabA(A, lds, 0,     row0, K, 0, 1, wid, lrow, cswz);

    for (int kt = 0; kt < NT; ++kt) {
        const int cur = kt & 1, nxt = cur ^ 1;
        const int Abase = cur * 32768, Bbase = cur * 32768 + 16384;
        const int An = nxt * 32768,   Bn = nxt * 32768 + 16384;
        const int kc = (kt + 1 < NT ? kt + 1 : kt) * 64;

        bf16x8 af[4][2], bfr[2][2];

        // phase 0: Q(0,0) — needs A0,B0; stage A0^{next}
        WAITBAR();
        load_fragsA<0>(lds, Abase, wm, r, quad, af);
        load_fragsB<0>(lds, Bbase, wn, r, quad, bfr);
        stage_slabA(A, lds, An, row0, K, kc, 0, wid, lrow, cswz);
        do_mfma<0, 0>(af, bfr, acc);

        // phase 1: Q(0,1) — needs B1; stage B0^{next}
        WAITBAR();
        load_fragsB<1>(lds, Bbase, wn, r, quad, bfr);
        stage_slabB(B, lds, Bn, col0, K, kc, 0, wid, lrow, cswz);
        do_mfma<0, 1>(af, bfr, acc);

        // phase 2: Q(1,1) — needs A1; stage B1^{next}
        WAITBAR();
        load_fragsA<1>(lds, Abase, wm, r, quad, af);
        stage_slabB(B, lds, Bn, col0, K, kc, 1, wid, lrow, cswz);
        do_mfma<1, 1>(af, bfr, acc);

        // phase 3: Q(1,0) — everything resident; stage A1^{next}; no wait
        load_fragsB<0>(lds, Bbase, wn, r, quad, bfr);
        stage_slabA(A, lds, An, row0, K, kc, 1, wid, lrow, cswz);
        do_mfma<1, 0>(af, bfr, acc);
    }

    // epilogue: D mapping col=lane&15, row=(lane>>4)*4+reg  [m89-verified]
    #pragma unroll
    for (int i = 0; i < 8; ++i) {
        #pragma unroll
        for (int j = 0; j < 4; ++j) {
            #pragma unroll
            for (int g = 0; g < 4; ++g) {
                int mr = row0 + wm * 128 + i * 16 + quad * 4 + g;
                int nc = col0 + wn * 64 + j * 16 + r;
                float v = acc[i][j][g];
                if (EPI == 0) {
                    if (nc < NP) Cb[(size_t)mr * NP + nc] = (bf16_t)v;
                    if (nc == 2 * S) dcol[mr] = v;
                } else if (EPI == 1) {
                    float Bm = (float)eb[(size_t)mr * NP + nc];
                    Cf[(size_t)mr * N + nc] = e0[mr] * Bm * v;
                } else {
                    float xc = (float)eb[(size_t)mr * N + nc];
                    Cf[(size_t)mr * N + nc] = v + e0[nc] * xc;
                }
            }
        }
    }
}

// ---------------------------------------------------------------------------
// chunked scan: h[l] = a[l]*h[l-1] + u[l],  a = exp(-exp(A_log[s]) * delta[l])
// ---------------------------------------------------------------------------
__global__ __launch_bounds__(256)
void scan_pass1(const float* __restrict__ Bu, const float* __restrict__ delta,
                const float* __restrict__ A_log,
                float* __restrict__ cP, float* __restrict__ cH)
{
    int s = blockIdx.x * 256 + threadIdx.x;
    int c = blockIdx.y;
    int b = blockIdx.z;
    float Acoef = -expf(A_log[s]);
    float P = 1.f, h = 0.f;
    int mbase = b * L + c * CL;
    for (int t = 0; t < CL; ++t) {
        float a = __expf(Acoef * delta[mbase + t]);
        float u = Bu[(size_t)(mbase + t) * S + s];
        h = fmaf(a, h, u);
        P *= a;
    }
    int id = b * S + s;
    cP[(size_t)id * NCH + c] = P;
    cH[(size_t)id * NCH + c] = h;
}

__global__ __launch_bounds__(256)
void scan_pass2(const float* __restrict__ cP, const float* __restrict__ cH,
                float* __restrict__ init)
{
    int id = blockIdx.x * 256 + threadIdx.x;
    if (id < Bb * S) {
        float h = 0.f;
        for (int c = 0; c < NCH; ++c) {
            init[(size_t)id * NCH + c] = h;
            h = fmaf(cP[(size_t)id * NCH + c], h, cH[(size_t)id * NCH + c]);
        }
    }
}

__global__ __launch_bounds__(256)
void scan_pass3(const float* __restrict__ Bu, const float* __restrict__ delta,
                const bf16_t* __restrict__ params_bf,
                const float* __restrict__ A_log,
                const float* __restrict__ init, bf16_t* __restrict__ hmod)
{
    int s = blockIdx.x * 256 + threadIdx.x;
    int c = blockIdx.y;
    int b = blockIdx.z;
    float Acoef = -expf(A_log[s]);
    float h = init[(size_t)(b * S + s) * NCH + c];
    int mbase = b * L + c * CL;
    for (int t = 0; t < CL; ++t) {
        int m = mbase + t;
        float a = __expf(Acoef * delta[m]);
        float u = Bu[(size_t)m * S + s];
        h = fmaf(a, h, u);
        float Cm = (float)params_bf[(size_t)m * NP + S + s];
        hmod[(size_t)m * S + s] = (bf16_t)(Cm * h);
    }
}

// ---------------------------------------------------------------------------
extern "C" void kernel_launch(void* const* d_in, const int* in_sizes, int n_in,
                              void* d_out, int out_size, void* d_ws, size_t ws_size,
                              hipStream_t stream)
{
    const float* x        = (const float*)d_in[0];
    const float* Wxproj   = (const float*)d_in[1];
    const float* Winproj  = (const float*)d_in[2];
    const float* Woutproj = (const float*)d_in[3];
    const float* conv_w   = (const float*)d_in[4];
    const float* conv_b   = (const float*)d_in[5];
    const float* A_log    = (const float*)d_in[6];
    const float* Dvec     = (const float*)d_in[7];
    float* out = (float*)d_out;

    // fp32 workspace
    float* ws_Bu    = (float*)d_ws;                       // M*S
    float* ws_dcol  = ws_Bu + (size_t)M * S;              // M
    float* ws_delta = ws_dcol + M;                        // M
    float* ws_cP    = ws_delta + M;                       // Bb*S*NCH
    float* ws_cH    = ws_cP + (size_t)Bb * S * NCH;
    float* ws_init  = ws_cH + (size_t)Bb * S * NCH;
    // bf16 workspace
    bf16_t* params_bf = (bf16_t*)(ws_init + (size_t)Bb * S * NCH); // M*NP
    bf16_t* x_bf      = params_bf + (size_t)M * NP;       // M*Dm
    bf16_t* hmod_bf   = x_bf;                             // M*S (alias, x_bf dead)
    bf16_t* xconv_bf  = x_bf + (size_t)M * Dm;            // M*Dm
    bf16_t* Wx_bf     = xconv_bf + (size_t)M * Dm;        // NP_PAD*Dm
    bf16_t* Win_bf    = Wx_bf + (size_t)NP_PAD * Dm;      // S*Dm
    bf16_t* Wout_bf   = Win_bf + (size_t)S * Dm;          // Dm*S

    // allow 128KB dynamic LDS for the 8-phase GEMMs (idempotent host call)
    hipFuncSetAttribute((const void*)gemm8p<0>,
                        hipFuncAttributeMaxDynamicSharedMemorySize, 131072);
    hipFuncSetAttribute((const void*)gemm8p<1>,
                        hipFuncAttributeMaxDynamicSharedMemorySize, 131072);
    hipFuncSetAttribute((const void*)gemm8p<2>,
                        hipFuncAttributeMaxDynamicSharedMemorySize, 131072);

    // 1. weight bf16 conversions (x handled by fused conv)
    long wx8 = (long)NP_PAD * Dm / 8;
    f2b_kernel<<<(wx8 + 255) / 256, 256, 0, stream>>>(Wxproj, Wx_bf, wx8, (long)NP * Dm);
    long wi8 = (long)S * Dm / 8;
    f2b_kernel<<<(wi8 + 255) / 256, 256, 0, stream>>>(Winproj, Win_bf, wi8, (long)S * Dm);
    f2b_kernel<<<(wi8 + 255) / 256, 256, 0, stream>>>(Woutproj, Wout_bf, wi8, (long)Dm * S);

    // 2. fused conv: x -> xconv_bf + x_bf
    conv_fused_kernel<<<(Bb * NTC * 512) / 256, 256, 0, stream>>>(
        x, conv_w, conv_b, xconv_bf, x_bf);

    // 3. GEMM1: ssm_params(bf16) = x @ Wxproj^T ; fp32 delta col
    dim3 g1(M / 256, NP_PAD / 256);
    gemm8p<0><<<g1, 512, 131072, stream>>>(x_bf, Wx_bf, NP, Dm, Dm / 64,
                                           params_bf, nullptr, ws_dcol,
                                           nullptr, nullptr);

    // 4. delta = softplus(dcol)
    delta_kernel<<<M / 256, 256, 0, stream>>>(ws_dcol, ws_delta);

    // 5. GEMM2: Bu = delta * Bmat * (x_conv @ Winproj^T)
    dim3 g2(M / 256, S / 256);
    gemm8p<1><<<g2, 512, 131072, stream>>>(xconv_bf, Win_bf, S, Dm, Dm / 64,
                                           nullptr, ws_Bu, nullptr,
                                           ws_delta, params_bf);

    // 6. chunked scan; h_mod = Cmat*h -> bf16
    dim3 gs(S / 256, NCH, Bb);
    scan_pass1<<<gs, 256, 0, stream>>>(ws_Bu, ws_delta, A_log, ws_cP, ws_cH);
    scan_pass2<<<(Bb * S) / 256, 256, 0, stream>>>(ws_cP, ws_cH, ws_init);
    scan_pass3<<<gs, 256, 0, stream>>>(ws_Bu, ws_delta, params_bf, A_log,
                                       ws_init, hmod_bf);

    // 7. GEMM3: out = h_mod @ Woutproj^T + D * x_conv
    dim3 g3(M / 256, Dm / 256);
    gemm8p<2><<<g3, 512, 131072, stream>>>(hmod_bf, Wout_bf, Dm, S, S / 64,
                                           nullptr, out, nullptr,
                                           Dvec, xconv_bf);
}

// Round 6
// 302.750 us; speedup vs baseline: 6.9636x; 1.0890x over previous
//
#include <hip/hip_runtime.h>
#include <math.h>

typedef __bf16 bf16_t;
typedef __bf16 bf16x8 __attribute__((ext_vector_type(8)));
typedef __bf16 bf16x4 __attribute__((ext_vector_type(4)));
typedef float  f32x4  __attribute__((ext_vector_type(4)));
typedef float  f32x16 __attribute__((ext_vector_type(16)));

// Problem shape (fixed by setup_inputs)
constexpr int Bb  = 4;
constexpr int L   = 4096;
constexpr int Dm  = 2048;
constexpr int S   = 512;
constexpr int M   = Bb * L;        // 16384
constexpr int NP  = 2 * S + 1;     // 1025
constexpr int PST = 1024;          // params stride (Bmat 0..511, Cmat 512..1023)
constexpr int CL  = 128;           // scan chunk length
constexpr int NCH = L / CL;        // 32
constexpr int TL  = 32;            // conv time-chunk per thread
constexpr int NTC = L / TL;        // 128

#define AS1 __attribute__((address_space(1)))
#define AS3 __attribute__((address_space(3)))

// ---------------------------------------------------------------------------
// float -> bf16 (RNE)
// ---------------------------------------------------------------------------
__global__ __launch_bounds__(256)
void f2b_kernel(const float* __restrict__ in, bf16_t* __restrict__ out,
                long out8, long in_elems)
{
    long i = (long)blockIdx.x * 256 + threadIdx.x;
    if (i >= out8) return;
    long e = i * 8;
    bf16x8 o;
    if (e + 8 <= in_elems) {
        float4 v0 = *(const float4*)(in + e);
        float4 v1 = *(const float4*)(in + e + 4);
        o[0] = (bf16_t)v0.x; o[1] = (bf16_t)v0.y;
        o[2] = (bf16_t)v0.z; o[3] = (bf16_t)v0.w;
        o[4] = (bf16_t)v1.x; o[5] = (bf16_t)v1.y;
        o[6] = (bf16_t)v1.z; o[7] = (bf16_t)v1.w;
    } else {
        #pragma unroll
        for (int k = 0; k < 8; ++k)
            o[k] = (e + k < in_elems) ? (bf16_t)in[e + k] : (bf16_t)0.f;
    }
    *(bf16x8*)(out + e) = o;
}

// ---------------------------------------------------------------------------
// Fused causal depthwise conv + x->bf16 (sliding window, x fetched once)
// ---------------------------------------------------------------------------
__global__ __launch_bounds__(256)
void conv_fused_kernel(const float* __restrict__ x, const float* __restrict__ w,
                       const float* __restrict__ bias,
                       bf16_t* __restrict__ xcb, bf16_t* __restrict__ xb)
{
    const float4* x4 = (const float4*)x;
    int g   = blockIdx.x * 256 + threadIdx.x;
    int d4  = g & 511;
    int rest = g >> 9;
    int c   = rest & (NTC - 1);
    int b   = rest >> 7;
    int d   = d4 * 4;

    float w0[4], w1[4], w2[4], w3[4];
    *(float4*)w0 = *(const float4*)&w[(d + 0) * 4];
    *(float4*)w1 = *(const float4*)&w[(d + 1) * 4];
    *(float4*)w2 = *(const float4*)&w[(d + 2) * 4];
    *(float4*)w3 = *(const float4*)&w[(d + 3) * 4];
    float4 bs = *(const float4*)&bias[d];

    const int l0 = c * TL;
    const size_t rowbase = (size_t)b * L;

    float4 win[3];
    #pragma unroll
    for (int i = 0; i < 3; ++i) {
        int lp = l0 - 3 + i;
        win[i] = (lp >= 0) ? x4[(rowbase + lp) * 512 + d4]
                           : make_float4(0.f, 0.f, 0.f, 0.f);
    }

    #pragma unroll
    for (int t = 0; t < TL; ++t) {
        size_t ri = (rowbase + l0 + t) * 512 + d4;
        float4 cur = x4[ri];
        float4 acc = bs;
        acc.x = fmaf(win[0].x, w0[0], acc.x);
        acc.y = fmaf(win[0].y, w1[0], acc.y);
        acc.z = fmaf(win[0].z, w2[0], acc.z);
        acc.w = fmaf(win[0].w, w3[0], acc.w);
        acc.x = fmaf(win[1].x, w0[1], acc.x);
        acc.y = fmaf(win[1].y, w1[1], acc.y);
        acc.z = fmaf(win[1].z, w2[1], acc.z);
        acc.w = fmaf(win[1].w, w3[1], acc.w);
        acc.x = fmaf(win[2].x, w0[2], acc.x);
        acc.y = fmaf(win[2].y, w1[2], acc.y);
        acc.z = fmaf(win[2].z, w2[2], acc.z);
        acc.w = fmaf(win[2].w, w3[2], acc.w);
        acc.x = fmaf(cur.x, w0[3], acc.x);
        acc.y = fmaf(cur.y, w1[3], acc.y);
        acc.z = fmaf(cur.z, w2[3], acc.z);
        acc.w = fmaf(cur.w, w3[3], acc.w);

        bf16x4 oc, ox;
        oc[0] = (bf16_t)acc.x; oc[1] = (bf16_t)acc.y;
        oc[2] = (bf16_t)acc.z; oc[3] = (bf16_t)acc.w;
        ox[0] = (bf16_t)cur.x; ox[1] = (bf16_t)cur.y;
        ox[2] = (bf16_t)cur.z; ox[3] = (bf16_t)cur.w;
        *(bf16x4*)(xcb + ri * 4) = oc;
        *(bf16x4*)(xb  + ri * 4) = ox;

        win[0] = win[1]; win[1] = win[2]; win[2] = cur;
    }
}

// ---------------------------------------------------------------------------
// delta[m] = softplus( dot(x_bf[m,:], wdt[:]) )  — one wave per row
// wdt = Wx_bf row 1024 (the delta projection row)
// ---------------------------------------------------------------------------
__global__ __launch_bounds__(256)
void gemv_delta(const bf16_t* __restrict__ x_bf, const bf16_t* __restrict__ wdt,
                float* __restrict__ delta)
{
    int m    = blockIdx.x * 4 + (threadIdx.x >> 6);
    int lane = threadIdx.x & 63;
    const bf16x8* xr = (const bf16x8*)(x_bf + (size_t)m * Dm);
    const bf16x8* wr = (const bf16x8*)wdt;
    float s = 0.f;
    #pragma unroll
    for (int i = 0; i < 4; ++i) {
        bf16x8 a = xr[i * 64 + lane];
        bf16x8 b = wr[i * 64 + lane];
        #pragma unroll
        for (int j = 0; j < 8; ++j) s += (float)a[j] * (float)b[j];
    }
    #pragma unroll
    for (int off = 32; off >= 1; off >>= 1) s += __shfl_xor(s, off, 64);
    if (lane == 0) {
        delta[m] = (s > 20.f) ? s : log1pf(__expf(s));
    }
}

// ---------------------------------------------------------------------------
// 256x256 tile, BK=64, 8 waves (2x4), 4-phase counted-vmcnt schedule,
// v_mfma_f32_32x32x16_bf16 (half the ds_read traffic of 16x16x32).
// LDS 128KB dynamic: [A0:0, B0:16384, A1:32768, B1:49152] (elems), each
// region 256 rows x 64 cols bf16, XOR-swizzled: (R,k) at R*64+(k^((R&7)<<3)).
// global_load_lds writes linearly -> global SOURCE inverse-swizzled (rule #21).
// Slab order per tile: A0, B0, B1, A1; quadrants (0,0),(0,1),(1,1),(1,0);
// every wait = counted vmcnt(4), never 0 (T4).
// ---------------------------------------------------------------------------
__device__ __forceinline__ void stage_slabA(const bf16_t* __restrict__ A,
    bf16_t* lds, int ldsbase, int row0, int K, int kcol, int mh,
    int wid, int lrow, int cswz)
{
    #pragma unroll
    for (int round = 0; round < 2; ++round) {
        int Rb = round * 128 + mh * 64 + wid * 8;
        const bf16_t* src = A + (size_t)(row0 + Rb + lrow) * K + kcol + cswz;
        __builtin_amdgcn_global_load_lds(
            (AS1 void*)src, (AS3 void*)(lds + ldsbase + Rb * 64), 16, 0, 0);
    }
}

__device__ __forceinline__ void stage_slabB(const bf16_t* __restrict__ B,
    bf16_t* lds, int ldsbase, int col0, int K, int kcol, int nh,
    int wid, int lrow, int cswz)
{
    #pragma unroll
    for (int round = 0; round < 2; ++round) {
        int c  = round * 8 + wid;
        int Rb = (c >> 2) * 64 + nh * 32 + (c & 3) * 8;
        const bf16_t* src = B + (size_t)(col0 + Rb + lrow) * K + kcol + cswz;
        __builtin_amdgcn_global_load_lds(
            (AS1 void*)src, (AS3 void*)(lds + ldsbase + Rb * 64), 16, 0, 0);
    }
}

template <int MH>
__device__ __forceinline__ void load_fragsA32(const bf16_t* lds, int Abase,
    int wm, int l31, int kh, bf16x8 (&af)[2][4])
{
    #pragma unroll
    for (int mi2 = 0; mi2 < 2; ++mi2) {
        const int R = wm * 128 + (MH * 2 + mi2) * 32 + l31;
        #pragma unroll
        for (int ks = 0; ks < 4; ++ks)
            af[mi2][ks] = *(const bf16x8*)(lds + Abase + R * 64 +
                            ((ks * 16 + kh * 8) ^ ((R & 7) << 3)));
    }
}

template <int NH>
__device__ __forceinline__ void load_fragsB32(const bf16_t* lds, int Bbase,
    int wn, int l31, int kh, bf16x8 (&bfr)[4])
{
    const int R = wn * 64 + NH * 32 + l31;
    #pragma unroll
    for (int ks = 0; ks < 4; ++ks)
        bfr[ks] = *(const bf16x8*)(lds + Bbase + R * 64 +
                    ((ks * 16 + kh * 8) ^ ((R & 7) << 3)));
}

template <int MH, int NH>
__device__ __forceinline__ void do_mfma32(bf16x8 (&af)[2][4], bf16x8 (&bfr)[4],
                                          f32x16 (&acc)[4][2])
{
    __builtin_amdgcn_s_setprio(1);
    #pragma unroll
    for (int ks = 0; ks < 4; ++ks)
        #pragma unroll
        for (int mi2 = 0; mi2 < 2; ++mi2)
            acc[MH * 2 + mi2][NH] = __builtin_amdgcn_mfma_f32_32x32x16_bf16(
                af[mi2][ks], bfr[ks], acc[MH * 2 + mi2][NH], 0, 0, 0);
    __builtin_amdgcn_s_setprio(0);
}

#define WAITBAR() do { \
    asm volatile("s_waitcnt vmcnt(4)" ::: "memory"); \
    __builtin_amdgcn_s_barrier(); } while (0)

// EPI 0: params: bf16 Cb[m*PST+n]
// EPI 1: Bu:     Cf[m*N+n] = e0[m] * bf2f(eb[m*PST+n]) * acc
// EPI 2: out:    Cf[m*N+n] = acc + e0[n] * bf2f(eb[m*N+n])
template <int EPI>
__global__ __launch_bounds__(512, 2)
void gemm8p(const bf16_t* __restrict__ A, const bf16_t* __restrict__ B,
            int N, int K, int NT,
            bf16_t* __restrict__ Cb, float* __restrict__ Cf,
            const float* __restrict__ e0, const bf16_t* __restrict__ eb)
{
    extern __shared__ __align__(16) char smem_raw[];
    bf16_t* lds = (bf16_t*)smem_raw;

    const int tid  = threadIdx.x;
    const int lane = tid & 63;
    const int wid  = tid >> 6;       // 0..7
    const int wm   = wid >> 2;       // 0..1
    const int wn   = wid & 3;        // 0..3
    const int l31  = lane & 31;
    const int kh   = lane >> 5;      // 0..1
    const int row0 = blockIdx.x * 256;
    const int col0 = blockIdx.y * 256;
    const int lrow = lane >> 3;                  // 0..7
    const int cswz = 8 * ((lane & 7) ^ lrow);    // inverse-swizzled src col

    f32x16 acc[4][2];
    #pragma unroll
    for (int i = 0; i < 4; ++i)
        #pragma unroll
        for (int j = 0; j < 2; ++j)
            #pragma unroll
            for (int g = 0; g < 16; ++g) acc[i][j][g] = 0.f;

    // prologue: tile 0 -> buffer 0; order A0, B0, B1, A1
    stage_slabA(A, lds, 0,     row0, K, 0, 0, wid, lrow, cswz);
    stage_slabB(B, lds, 16384, col0, K, 0, 0, wid, lrow, cswz);
    stage_slabB(B, lds, 16384, col0, K, 0, 1, wid, lrow, cswz);
    stage_slabA(A, lds, 0,     row0, K, 0, 1, wid, lrow, cswz);

    for (int kt = 0; kt < NT; ++kt) {
        const int cur = kt & 1, nxt = cur ^ 1;
        const int Abase = cur * 32768, Bbase = cur * 32768 + 16384;
        const int An = nxt * 32768,   Bn = nxt * 32768 + 16384;
        const int kc = (kt + 1 < NT ? kt + 1 : kt) * 64;

        bf16x8 af[2][4], bfr[4];

        // phase 0: Q(0,0) — needs A0,B0; stage A0^{next}
        WAITBAR();
        load_fragsA32<0>(lds, Abase, wm, l31, kh, af);
        load_fragsB32<0>(lds, Bbase, wn, l31, kh, bfr);
        stage_slabA(A, lds, An, row0, K, kc, 0, wid, lrow, cswz);
        do_mfma32<0, 0>(af, bfr, acc);

        // phase 1: Q(0,1) — needs B1; stage B0^{next}
        WAITBAR();
        load_fragsB32<1>(lds, Bbase, wn, l31, kh, bfr);
        stage_slabB(B, lds, Bn, col0, K, kc, 0, wid, lrow, cswz);
        do_mfma32<0, 1>(af, bfr, acc);

        // phase 2: Q(1,1) — needs A1; stage B1^{next}
        WAITBAR();
        load_fragsA32<1>(lds, Abase, wm, l31, kh, af);
        stage_slabB(B, lds, Bn, col0, K, kc, 1, wid, lrow, cswz);
        do_mfma32<1, 1>(af, bfr, acc);

        // phase 3: Q(1,0) — everything resident; stage A1^{next}; no wait
        load_fragsB32<0>(lds, Bbase, wn, l31, kh, bfr);
        stage_slabA(A, lds, An, row0, K, kc, 1, wid, lrow, cswz);
        do_mfma32<1, 0>(af, bfr, acc);
    }

    // epilogue: 32x32 D mapping col=lane&31, row=(rg&3)+8*(rg>>2)+4*(lane>>5)
    // [m74/m101-verified]
    #pragma unroll
    for (int mi = 0; mi < 4; ++mi) {
        #pragma unroll
        for (int nj = 0; nj < 2; ++nj) {
            #pragma unroll
            for (int rg = 0; rg < 16; ++rg) {
                int mr = row0 + wm * 128 + mi * 32 + (rg & 3) + 8 * (rg >> 2) + 4 * kh;
                int nc = col0 + wn * 64 + nj * 32 + l31;
                float v = acc[mi][nj][rg];
                if (EPI == 0) {
                    Cb[(size_t)mr * PST + nc] = (bf16_t)v;
                } else if (EPI == 1) {
                    float Bm = (float)eb[(size_t)mr * PST + nc];
                    Cf[(size_t)mr * N + nc] = e0[mr] * Bm * v;
                } else {
                    float xc = (float)eb[(size_t)mr * N + nc];
                    Cf[(size_t)mr * N + nc] = v + e0[nc] * xc;
                }
            }
        }
    }
}

// ---------------------------------------------------------------------------
// chunked scan: h[l] = a[l]*h[l-1] + u[l],  a = exp(-exp(A_log[s]) * delta[l])
// ---------------------------------------------------------------------------
__global__ __launch_bounds__(256)
void scan_pass1(const float* __restrict__ Bu, const float* __restrict__ delta,
                const float* __restrict__ A_log,
                float* __restrict__ cP, float* __restrict__ cH)
{
    int s = blockIdx.x * 256 + threadIdx.x;
    int c = blockIdx.y;
    int b = blockIdx.z;
    float Acoef = -expf(A_log[s]);
    float P = 1.f, h = 0.f;
    int mbase = b * L + c * CL;
    for (int t = 0; t < CL; ++t) {
        float a = __expf(Acoef * delta[mbase + t]);
        float u = Bu[(size_t)(mbase + t) * S + s];
        h = fmaf(a, h, u);
        P *= a;
    }
    int id = b * S + s;
    cP[(size_t)id * NCH + c] = P;
    cH[(size_t)id * NCH + c] = h;
}

__global__ __launch_bounds__(256)
void scan_pass2(const float* __restrict__ cP, const float* __restrict__ cH,
                float* __restrict__ init)
{
    int id = blockIdx.x * 256 + threadIdx.x;
    if (id < Bb * S) {
        float h = 0.f;
        for (int c = 0; c < NCH; ++c) {
            init[(size_t)id * NCH + c] = h;
            h = fmaf(cP[(size_t)id * NCH + c], h, cH[(size_t)id * NCH + c]);
        }
    }
}

__global__ __launch_bounds__(256)
void scan_pass3(const float* __restrict__ Bu, const float* __restrict__ delta,
                const bf16_t* __restrict__ params_bf,
                const float* __restrict__ A_log,
                const float* __restrict__ init, bf16_t* __restrict__ hmod)
{
    int s = blockIdx.x * 256 + threadIdx.x;
    int c = blockIdx.y;
    int b = blockIdx.z;
    float Acoef = -expf(A_log[s]);
    float h = init[(size_t)(b * S + s) * NCH + c];
    int mbase = b * L + c * CL;
    for (int t = 0; t < CL; ++t) {
        int m = mbase + t;
        float a = __expf(Acoef * delta[m]);
        float u = Bu[(size_t)m * S + s];
        h = fmaf(a, h, u);
        float Cm = (float)params_bf[(size_t)m * PST + S + s];
        hmod[(size_t)m * S + s] = (bf16_t)(Cm * h);
    }
}

// ---------------------------------------------------------------------------
extern "C" void kernel_launch(void* const* d_in, const int* in_sizes, int n_in,
                              void* d_out, int out_size, void* d_ws, size_t ws_size,
                              hipStream_t stream)
{
    const float* x        = (const float*)d_in[0];
    const float* Wxproj   = (const float*)d_in[1];
    const float* Winproj  = (const float*)d_in[2];
    const float* Woutproj = (const float*)d_in[3];
    const float* conv_w   = (const float*)d_in[4];
    const float* conv_b   = (const float*)d_in[5];
    const float* A_log    = (const float*)d_in[6];
    const float* Dvec     = (const float*)d_in[7];
    float* out = (float*)d_out;

    // fp32 workspace
    float* ws_Bu    = (float*)d_ws;                       // M*S
    float* ws_delta = ws_Bu + (size_t)M * S;              // M
    float* ws_cP    = ws_delta + M;                       // Bb*S*NCH
    float* ws_cH    = ws_cP + (size_t)Bb * S * NCH;
    float* ws_init  = ws_cH + (size_t)Bb * S * NCH;
    // bf16 workspace
    bf16_t* params_bf = (bf16_t*)(ws_init + (size_t)Bb * S * NCH); // M*PST
    bf16_t* x_bf      = params_bf + (size_t)M * PST;      // M*Dm
    bf16_t* hmod_bf   = x_bf;                             // M*S (alias; x_bf dead after gemv)
    bf16_t* xconv_bf  = x_bf + (size_t)M * Dm;            // M*Dm
    bf16_t* Wx_bf     = xconv_bf + (size_t)M * Dm;        // NP*Dm (1025 rows)
    bf16_t* Win_bf    = Wx_bf + (size_t)NP * Dm;          // S*Dm
    bf16_t* Wout_bf   = Win_bf + (size_t)S * Dm;          // Dm*S

    hipFuncSetAttribute((const void*)gemm8p<0>,
                        hipFuncAttributeMaxDynamicSharedMemorySize, 131072);
    hipFuncSetAttribute((const void*)gemm8p<1>,
                        hipFuncAttributeMaxDynamicSharedMemorySize, 131072);
    hipFuncSetAttribute((const void*)gemm8p<2>,
                        hipFuncAttributeMaxDynamicSharedMemorySize, 131072);

    // 1. weight bf16 conversions (x handled by fused conv)
    long wx8 = (long)NP * Dm / 8;   // 262400, exact
    f2b_kernel<<<(wx8 + 255) / 256, 256, 0, stream>>>(Wxproj, Wx_bf, wx8, (long)NP * Dm);
    long wi8 = (long)S * Dm / 8;
    f2b_kernel<<<(wi8 + 255) / 256, 256, 0, stream>>>(Winproj, Win_bf, wi8, (long)S * Dm);
    f2b_kernel<<<(wi8 + 255) / 256, 256, 0, stream>>>(Woutproj, Wout_bf, wi8, (long)Dm * S);

    // 2. fused conv: x -> xconv_bf + x_bf
    conv_fused_kernel<<<(Bb * NTC * 512) / 256, 256, 0, stream>>>(
        x, conv_w, conv_b, xconv_bf, x_bf);

    // 3. GEMM1: params(bf16, stride 1024) = x @ Wxproj[0:1024]^T  (grid = 256 blocks exact)
    dim3 g1(M / 256, PST / 256);
    gemm8p<0><<<g1, 512, 131072, stream>>>(x_bf, Wx_bf, PST, Dm, Dm / 64,
                                           params_bf, nullptr, nullptr, nullptr);

    // 4. delta = softplus(x . Wxproj[1024])  — fused GEMV
    gemv_delta<<<M / 4, 256, 0, stream>>>(x_bf, Wx_bf + (size_t)PST * Dm, ws_delta);

    // 5. GEMM2: Bu = delta * Bmat * (x_conv @ Winproj^T)
    dim3 g2(M / 256, S / 256);
    gemm8p<1><<<g2, 512, 131072, stream>>>(xconv_bf, Win_bf, S, Dm, Dm / 64,
                                           nullptr, ws_Bu, ws_delta, params_bf);

    // 6. chunked scan; h_mod = Cmat*h -> bf16
    dim3 gs(S / 256, NCH, Bb);
    scan_pass1<<<gs, 256, 0, stream>>>(ws_Bu, ws_delta, A_log, ws_cP, ws_cH);
    scan_pass2<<<(Bb * S) / 256, 256, 0, stream>>>(ws_cP, ws_cH, ws_init);
    scan_pass3<<<gs, 256, 0, stream>>>(ws_Bu, ws_delta, params_bf, A_log,
                                       ws_init, hmod_bf);

    // 7. GEMM3: out = h_mod @ Woutproj^T + D * x_conv
    dim3 g3(M / 256, Dm / 256);
    gemm8p<2><<<g3, 512, 131072, stream>>>(hmod_bf, Wout_bf, Dm, S, S / 64,
                                           nullptr, out, Dvec, xconv_bf);
}

// Round 7
// 293.492 us; speedup vs baseline: 7.1832x; 1.0315x over previous
//
#include <hip/hip_runtime.h>
#include <math.h>

typedef __bf16 bf16_t;
typedef __bf16 bf16x8 __attribute__((ext_vector_type(8)));
typedef __bf16 bf16x4 __attribute__((ext_vector_type(4)));
typedef float  f32x4  __attribute__((ext_vector_type(4)));
typedef float  f32x16 __attribute__((ext_vector_type(16)));

// Problem shape (fixed by setup_inputs)
constexpr int Bb  = 4;
constexpr int L   = 4096;
constexpr int Dm  = 2048;
constexpr int S   = 512;
constexpr int M   = Bb * L;        // 16384
constexpr int NP  = 2 * S + 1;     // 1025
constexpr int PST = 1024;          // params stride (Bmat 0..511, Cmat 512..1023)
constexpr int CL  = 128;           // scan chunk length
constexpr int NCH = L / CL;        // 32
constexpr int TL  = 32;            // conv time-chunk per thread
constexpr int NTC = L / TL;        // 128

#define AS1 __attribute__((address_space(1)))
#define AS3 __attribute__((address_space(3)))

// ---------------------------------------------------------------------------
// float -> bf16 (RNE)
// ---------------------------------------------------------------------------
__global__ __launch_bounds__(256)
void f2b_kernel(const float* __restrict__ in, bf16_t* __restrict__ out,
                long out8, long in_elems)
{
    long i = (long)blockIdx.x * 256 + threadIdx.x;
    if (i >= out8) return;
    long e = i * 8;
    bf16x8 o;
    if (e + 8 <= in_elems) {
        float4 v0 = *(const float4*)(in + e);
        float4 v1 = *(const float4*)(in + e + 4);
        o[0] = (bf16_t)v0.x; o[1] = (bf16_t)v0.y;
        o[2] = (bf16_t)v0.z; o[3] = (bf16_t)v0.w;
        o[4] = (bf16_t)v1.x; o[5] = (bf16_t)v1.y;
        o[6] = (bf16_t)v1.z; o[7] = (bf16_t)v1.w;
    } else {
        #pragma unroll
        for (int k = 0; k < 8; ++k)
            o[k] = (e + k < in_elems) ? (bf16_t)in[e + k] : (bf16_t)0.f;
    }
    *(bf16x8*)(out + e) = o;
}

// ---------------------------------------------------------------------------
// Fused causal depthwise conv + x->bf16. Each thread: 8 channels x 32 steps.
// Reads 32B/lane/step (2KB/wave contiguous), writes 16B/lane/step per array.
// ---------------------------------------------------------------------------
__global__ __launch_bounds__(256)
void conv_fused8(const float* __restrict__ x, const float* __restrict__ w,
                 const float* __restrict__ bias,
                 bf16_t* __restrict__ xcb, bf16_t* __restrict__ xb)
{
    const float4* x4 = (const float4*)x;
    int g    = blockIdx.x * 256 + threadIdx.x;   // 0 .. Bb*NTC*256-1
    int d8   = g & 255;
    int rest = g >> 8;
    int c    = rest & (NTC - 1);
    int b    = rest >> 7;
    int d    = d8 * 8;

    float wv[8][4];
    #pragma unroll
    for (int j = 0; j < 8; ++j)
        *(float4*)wv[j] = *(const float4*)&w[(d + j) * 4];
    float bsv[8];
    *(float4*)&bsv[0] = *(const float4*)&bias[d];
    *(float4*)&bsv[4] = *(const float4*)&bias[d + 4];

    const int l0 = c * TL;
    const size_t rowbase = (size_t)b * L;

    float win[3][8];
    #pragma unroll
    for (int i = 0; i < 3; ++i) {
        int lp = l0 - 3 + i;
        if (lp >= 0) {
            size_t rb4 = (rowbase + lp) * 512 + d8 * 2;
            *(float4*)&win[i][0] = x4[rb4];
            *(float4*)&win[i][4] = x4[rb4 + 1];
        } else {
            #pragma unroll
            for (int j = 0; j < 8; ++j) win[i][j] = 0.f;
        }
    }

    for (int t = 0; t < TL; ++t) {
        size_t m = rowbase + l0 + t;
        size_t rb4 = m * 512 + d8 * 2;
        float cur[8];
        *(float4*)&cur[0] = x4[rb4];
        *(float4*)&cur[4] = x4[rb4 + 1];

        bf16x8 oc, ox;
        #pragma unroll
        for (int j = 0; j < 8; ++j) {
            float a = bsv[j];
            a = fmaf(win[0][j], wv[j][0], a);
            a = fmaf(win[1][j], wv[j][1], a);
            a = fmaf(win[2][j], wv[j][2], a);
            a = fmaf(cur[j],    wv[j][3], a);
            oc[j] = (bf16_t)a;
            ox[j] = (bf16_t)cur[j];
        }
        *(bf16x8*)(xcb + m * Dm + d) = oc;
        *(bf16x8*)(xb  + m * Dm + d) = ox;

        #pragma unroll
        for (int j = 0; j < 8; ++j) {
            win[0][j] = win[1][j]; win[1][j] = win[2][j]; win[2][j] = cur[j];
        }
    }
}

// ---------------------------------------------------------------------------
// delta[m] = softplus( dot(x_bf[m,:], wdt[:]) )  — one wave per row
// ---------------------------------------------------------------------------
__global__ __launch_bounds__(256)
void gemv_delta(const bf16_t* __restrict__ x_bf, const bf16_t* __restrict__ wdt,
                float* __restrict__ delta)
{
    int m    = blockIdx.x * 4 + (threadIdx.x >> 6);
    int lane = threadIdx.x & 63;
    const bf16x8* xr = (const bf16x8*)(x_bf + (size_t)m * Dm);
    const bf16x8* wr = (const bf16x8*)wdt;
    float s = 0.f;
    #pragma unroll
    for (int i = 0; i < 4; ++i) {
        bf16x8 a = xr[i * 64 + lane];
        bf16x8 b = wr[i * 64 + lane];
        #pragma unroll
        for (int j = 0; j < 8; ++j) s += (float)a[j] * (float)b[j];
    }
    #pragma unroll
    for (int off = 32; off >= 1; off >>= 1) s += __shfl_xor(s, off, 64);
    if (lane == 0) {
        delta[m] = (s > 20.f) ? s : log1pf(__expf(s));
    }
}

// ---------------------------------------------------------------------------
// Shared GEMM machinery: XOR-swizzled LDS regions of R rows x 64 cols bf16,
// (R,k) at R*64 + (k ^ ((R&7)<<3)); global SOURCE inverse-swizzled (rule #21).
// ---------------------------------------------------------------------------
__device__ __forceinline__ void stage_slabA(const bf16_t* __restrict__ A,
    bf16_t* lds, int ldsbase, int row0, int K, int kcol, int mh,
    int wid, int lrow, int cswz)
{
    #pragma unroll
    for (int round = 0; round < 2; ++round) {
        int Rb = round * 128 + mh * 64 + wid * 8;
        const bf16_t* src = A + (size_t)(row0 + Rb + lrow) * K + kcol + cswz;
        __builtin_amdgcn_global_load_lds(
            (AS1 void*)src, (AS3 void*)(lds + ldsbase + Rb * 64), 16, 0, 0);
    }
}

// 128-row A slab (whole tile in one call, 2 loads/thread)
__device__ __forceinline__ void stage_slabA128(const bf16_t* __restrict__ A,
    bf16_t* lds, int ldsbase, int row0, int K, int kcol,
    int wid, int lrow, int cswz)
{
    #pragma unroll
    for (int round = 0; round < 2; ++round) {
        int Rb = round * 64 + wid * 8;
        const bf16_t* src = A + (size_t)(row0 + Rb + lrow) * K + kcol + cswz;
        __builtin_amdgcn_global_load_lds(
            (AS1 void*)src, (AS3 void*)(lds + ldsbase + Rb * 64), 16, 0, 0);
    }
}

__device__ __forceinline__ void stage_slabB(const bf16_t* __restrict__ B,
    bf16_t* lds, int ldsbase, int col0, int K, int kcol, int nh,
    int wid, int lrow, int cswz)
{
    #pragma unroll
    for (int round = 0; round < 2; ++round) {
        int c  = round * 8 + wid;
        int Rb = (c >> 2) * 64 + nh * 32 + (c & 3) * 8;
        const bf16_t* src = B + (size_t)(col0 + Rb + lrow) * K + kcol + cswz;
        __builtin_amdgcn_global_load_lds(
            (AS1 void*)src, (AS3 void*)(lds + ldsbase + Rb * 64), 16, 0, 0);
    }
}

template <int MH>
__device__ __forceinline__ void load_fragsA32(const bf16_t* lds, int Abase,
    int wm, int l31, int kh, bf16x8 (&af)[2][4])
{
    #pragma unroll
    for (int mi2 = 0; mi2 < 2; ++mi2) {
        const int R = wm * 128 + (MH * 2 + mi2) * 32 + l31;
        #pragma unroll
        for (int ks = 0; ks < 4; ++ks)
            af[mi2][ks] = *(const bf16x8*)(lds + Abase + R * 64 +
                            ((ks * 16 + kh * 8) ^ ((R & 7) << 3)));
    }
}

template <int MI>
__device__ __forceinline__ void load_fragsA32h(const bf16_t* lds, int Abase,
    int wm, int l31, int kh, bf16x8 (&af)[4])
{
    const int R = wm * 64 + MI * 32 + l31;
    #pragma unroll
    for (int ks = 0; ks < 4; ++ks)
        af[ks] = *(const bf16x8*)(lds + Abase + R * 64 +
                    ((ks * 16 + kh * 8) ^ ((R & 7) << 3)));
}

template <int NH>
__device__ __forceinline__ void load_fragsB32(const bf16_t* lds, int Bbase,
    int wn, int l31, int kh, bf16x8 (&bfr)[4])
{
    const int R = wn * 64 + NH * 32 + l31;
    #pragma unroll
    for (int ks = 0; ks < 4; ++ks)
        bfr[ks] = *(const bf16x8*)(lds + Bbase + R * 64 +
                    ((ks * 16 + kh * 8) ^ ((R & 7) << 3)));
}

template <int MH, int NH>
__device__ __forceinline__ void do_mfma32(bf16x8 (&af)[2][4], bf16x8 (&bfr)[4],
                                          f32x16 (&acc)[4][2])
{
    __builtin_amdgcn_s_setprio(1);
    #pragma unroll
    for (int ks = 0; ks < 4; ++ks)
        #pragma unroll
        for (int mi2 = 0; mi2 < 2; ++mi2)
            acc[MH * 2 + mi2][NH] = __builtin_amdgcn_mfma_f32_32x32x16_bf16(
                af[mi2][ks], bfr[ks], acc[MH * 2 + mi2][NH], 0, 0, 0);
    __builtin_amdgcn_s_setprio(0);
}

template <int MI, int NJ>
__device__ __forceinline__ void do_mfma32h(bf16x8 (&af)[4], bf16x8 (&bfr)[4],
                                           f32x16 (&acc)[2][2])
{
    __builtin_amdgcn_s_setprio(1);
    #pragma unroll
    for (int ks = 0; ks < 4; ++ks)
        acc[MI][NJ] = __builtin_amdgcn_mfma_f32_32x32x16_bf16(
            af[ks], bfr[ks], acc[MI][NJ], 0, 0, 0);
    __builtin_amdgcn_s_setprio(0);
}

#define WAITBAR(N) do { \
    asm volatile("s_waitcnt vmcnt(" #N ")" ::: "memory"); \
    __builtin_amdgcn_s_barrier(); } while (0)

// ---------------------------------------------------------------------------
// 256x256 tile, BK=64, 8 waves (2x4), 4-phase counted-vmcnt schedule.
// EPI 0: params: bf16 Cb[m*PST+n]
// EPI 2: out:    Cf[m*N+n] = acc + e0[n] * bf2f(eb[m*N+n])
// ---------------------------------------------------------------------------
template <int EPI>
__global__ __launch_bounds__(512, 2)
void gemm8p(const bf16_t* __restrict__ A, const bf16_t* __restrict__ B,
            int N, int K, int NT,
            bf16_t* __restrict__ Cb, float* __restrict__ Cf,
            const float* __restrict__ e0, const bf16_t* __restrict__ eb)
{
    extern __shared__ __align__(16) char smem_raw[];
    bf16_t* lds = (bf16_t*)smem_raw;

    const int tid  = threadIdx.x;
    const int lane = tid & 63;
    const int wid  = tid >> 6;
    const int wm   = wid >> 2;
    const int wn   = wid & 3;
    const int l31  = lane & 31;
    const int kh   = lane >> 5;
    const int row0 = blockIdx.x * 256;
    const int col0 = blockIdx.y * 256;
    const int lrow = lane >> 3;
    const int cswz = 8 * ((lane & 7) ^ lrow);

    f32x16 acc[4][2];
    #pragma unroll
    for (int i = 0; i < 4; ++i)
        #pragma unroll
        for (int j = 0; j < 2; ++j)
            #pragma unroll
            for (int g = 0; g < 16; ++g) acc[i][j][g] = 0.f;

    // prologue: tile 0 -> buffer 0; order A0, B0, B1, A1
    stage_slabA(A, lds, 0,     row0, K, 0, 0, wid, lrow, cswz);
    stage_slabB(B, lds, 16384, col0, K, 0, 0, wid, lrow, cswz);
    stage_slabB(B, lds, 16384, col0, K, 0, 1, wid, lrow, cswz);
    stage_slabA(A, lds, 0,     row0, K, 0, 1, wid, lrow, cswz);

    for (int kt = 0; kt < NT; ++kt) {
        const int cur = kt & 1, nxt = cur ^ 1;
        const int Abase = cur * 32768, Bbase = cur * 32768 + 16384;
        const int An = nxt * 32768,   Bn = nxt * 32768 + 16384;
        const int kc = (kt + 1 < NT ? kt + 1 : kt) * 64;

        bf16x8 af[2][4], bfr[4];

        // phase 0: Q(0,0) — needs A0,B0; stage A0^{next}
        WAITBAR(4);
        load_fragsA32<0>(lds, Abase, wm, l31, kh, af);
        load_fragsB32<0>(lds, Bbase, wn, l31, kh, bfr);
        stage_slabA(A, lds, An, row0, K, kc, 0, wid, lrow, cswz);
        do_mfma32<0, 0>(af, bfr, acc);

        // phase 1: Q(0,1) — needs B1; stage B0^{next}
        WAITBAR(4);
        load_fragsB32<1>(lds, Bbase, wn, l31, kh, bfr);
        stage_slabB(B, lds, Bn, col0, K, kc, 0, wid, lrow, cswz);
        do_mfma32<0, 1>(af, bfr, acc);

        // phase 2: Q(1,1) — needs A1; stage B1^{next}
        WAITBAR(4);
        load_fragsA32<1>(lds, Abase, wm, l31, kh, af);
        stage_slabB(B, lds, Bn, col0, K, kc, 1, wid, lrow, cswz);
        do_mfma32<1, 1>(af, bfr, acc);

        // phase 3: Q(1,0) — everything resident; stage A1^{next}; no wait
        load_fragsB32<0>(lds, Bbase, wn, l31, kh, bfr);
        stage_slabA(A, lds, An, row0, K, kc, 1, wid, lrow, cswz);
        do_mfma32<1, 0>(af, bfr, acc);
    }

    // epilogue: 32x32 D map col=lane&31, row=(rg&3)+8*(rg>>2)+4*(lane>>5)
    #pragma unroll
    for (int mi = 0; mi < 4; ++mi) {
        #pragma unroll
        for (int nj = 0; nj < 2; ++nj) {
            #pragma unroll
            for (int rg = 0; rg < 16; ++rg) {
                int mr = row0 + wm * 128 + mi * 32 + (rg & 3) + 8 * (rg >> 2) + 4 * kh;
                int nc = col0 + wn * 64 + nj * 32 + l31;
                float v = acc[mi][nj][rg];
                if (EPI == 0) {
                    Cb[(size_t)mr * PST + nc] = (bf16_t)v;
                } else {
                    float xc = (float)eb[(size_t)mr * N + nc];
                    Cf[(size_t)mr * N + nc] = v + e0[nc] * xc;
                }
            }
        }
    }
}

// ---------------------------------------------------------------------------
// 128x256 tile variant (full-machine grid for N=512 GEMM2), BK=64, 8 waves
// 2x4, each wave 64x64. Stages per tile: A(whole), B0, B1 = 6 loads/thread.
// Waits: vmcnt(2) at phases 0,1 only (A+B0 / B1); phases 2,3 resident.
// EPI 1 only: Cf[m*N+n] = e0[m] * bf2f(eb[m*PST+n]) * acc
// ---------------------------------------------------------------------------
__global__ __launch_bounds__(512, 2)
void gemm8ph(const bf16_t* __restrict__ A, const bf16_t* __restrict__ B,
             int N, int K, int NT,
             float* __restrict__ Cf,
             const float* __restrict__ e0, const bf16_t* __restrict__ eb)
{
    extern __shared__ __align__(16) char smem_raw[];
    bf16_t* lds = (bf16_t*)smem_raw;

    const int tid  = threadIdx.x;
    const int lane = tid & 63;
    const int wid  = tid >> 6;
    const int wm   = wid >> 2;       // 0..1 (64-row half)
    const int wn   = wid & 3;        // 0..3
    const int l31  = lane & 31;
    const int kh   = lane >> 5;
    const int row0 = blockIdx.x * 128;
    const int col0 = blockIdx.y * 256;
    const int lrow = lane >> 3;
    const int cswz = 8 * ((lane & 7) ^ lrow);

    // buffer stride 24576 elems: A (128x64) at 0, B (256x64) at 8192
    f32x16 acc[2][2];
    #pragma unroll
    for (int i = 0; i < 2; ++i)
        #pragma unroll
        for (int j = 0; j < 2; ++j)
            #pragma unroll
            for (int g = 0; g < 16; ++g) acc[i][j][g] = 0.f;

    // prologue: tile 0 -> buffer 0; order A, B0, B1
    stage_slabA128(A, lds, 0,    row0, K, 0, wid, lrow, cswz);
    stage_slabB(B, lds, 8192, col0, K, 0, 0, wid, lrow, cswz);
    stage_slabB(B, lds, 8192, col0, K, 0, 1, wid, lrow, cswz);

    for (int kt = 0; kt < NT; ++kt) {
        const int cur = kt & 1, nxt = cur ^ 1;
        const int Abase = cur * 24576, Bbase = cur * 24576 + 8192;
        const int An = nxt * 24576,   Bn = nxt * 24576 + 8192;
        const int kc = (kt + 1 < NT ? kt + 1 : kt) * 64;

        bf16x8 af[4], bfr[4];

        // phase 0: (0,0) — needs A,B0; stage A^{next}
        WAITBAR(2);
        load_fragsA32h<0>(lds, Abase, wm, l31, kh, af);
        load_fragsB32<0>(lds, Bbase, wn, l31, kh, bfr);
        stage_slabA128(A, lds, An, row0, K, kc, wid, lrow, cswz);
        do_mfma32h<0, 0>(af, bfr, acc);

        // phase 1: (0,1) — needs B1; stage B0^{next}
        WAITBAR(2);
        load_fragsB32<1>(lds, Bbase, wn, l31, kh, bfr);
        stage_slabB(B, lds, Bn, col0, K, kc, 0, wid, lrow, cswz);
        do_mfma32h<0, 1>(af, bfr, acc);

        // phase 2: (1,1) — resident; stage B1^{next}; no wait
        load_fragsA32h<1>(lds, Abase, wm, l31, kh, af);
        stage_slabB(B, lds, Bn, col0, K, kc, 1, wid, lrow, cswz);
        do_mfma32h<1, 1>(af, bfr, acc);

        // phase 3: (1,0) — resident; no wait, no stage
        load_fragsB32<0>(lds, Bbase, wn, l31, kh, bfr);
        do_mfma32h<1, 0>(af, bfr, acc);
    }

    #pragma unroll
    for (int mi = 0; mi < 2; ++mi) {
        #pragma unroll
        for (int nj = 0; nj < 2; ++nj) {
            #pragma unroll
            for (int rg = 0; rg < 16; ++rg) {
                int mr = row0 + wm * 64 + mi * 32 + (rg & 3) + 8 * (rg >> 2) + 4 * kh;
                int nc = col0 + wn * 64 + nj * 32 + l31;
                float Bm = (float)eb[(size_t)mr * PST + nc];
                Cf[(size_t)mr * N + nc] = e0[mr] * Bm * acc[mi][nj][rg];
            }
        }
    }
}

// ---------------------------------------------------------------------------
// chunked scan: h[l] = a[l]*h[l-1] + u[l],  a = exp(-exp(A_log[s]) * delta[l])
// ---------------------------------------------------------------------------
__global__ __launch_bounds__(256)
void scan_pass1(const float* __restrict__ Bu, const float* __restrict__ delta,
                const float* __restrict__ A_log,
                float* __restrict__ cP, float* __restrict__ cH)
{
    int s = blockIdx.x * 256 + threadIdx.x;
    int c = blockIdx.y;
    int b = blockIdx.z;
    float Acoef = -expf(A_log[s]);
    float P = 1.f, h = 0.f;
    int mbase = b * L + c * CL;
    for (int t = 0; t < CL; ++t) {
        float a = __expf(Acoef * delta[mbase + t]);
        float u = Bu[(size_t)(mbase + t) * S + s];
        h = fmaf(a, h, u);
        P *= a;
    }
    int id = b * S + s;
    cP[(size_t)id * NCH + c] = P;
    cH[(size_t)id * NCH + c] = h;
}

__global__ __launch_bounds__(256)
void scan_pass2(const float* __restrict__ cP, const float* __restrict__ cH,
                float* __restrict__ init)
{
    int id = blockIdx.x * 256 + threadIdx.x;
    if (id < Bb * S) {
        float h = 0.f;
        for (int c = 0; c < NCH; ++c) {
            init[(size_t)id * NCH + c] = h;
            h = fmaf(cP[(size_t)id * NCH + c], h, cH[(size_t)id * NCH + c]);
        }
    }
}

__global__ __launch_bounds__(256)
void scan_pass3(const float* __restrict__ Bu, const float* __restrict__ delta,
                const bf16_t* __restrict__ params_bf,
                const float* __restrict__ A_log,
                const float* __restrict__ init, bf16_t* __restrict__ hmod)
{
    int s = blockIdx.x * 256 + threadIdx.x;
    int c = blockIdx.y;
    int b = blockIdx.z;
    float Acoef = -expf(A_log[s]);
    float h = init[(size_t)(b * S + s) * NCH + c];
    int mbase = b * L + c * CL;
    for (int t = 0; t < CL; ++t) {
        int m = mbase + t;
        float a = __expf(Acoef * delta[m]);
        float u = Bu[(size_t)m * S + s];
        h = fmaf(a, h, u);
        float Cm = (float)params_bf[(size_t)m * PST + S + s];
        hmod[(size_t)m * S + s] = (bf16_t)(Cm * h);
    }
}

// ---------------------------------------------------------------------------
extern "C" void kernel_launch(void* const* d_in, const int* in_sizes, int n_in,
                              void* d_out, int out_size, void* d_ws, size_t ws_size,
                              hipStream_t stream)
{
    const float* x        = (const float*)d_in[0];
    const float* Wxproj   = (const float*)d_in[1];
    const float* Winproj  = (const float*)d_in[2];
    const float* Woutproj = (const float*)d_in[3];
    const float* conv_w   = (const float*)d_in[4];
    const float* conv_b   = (const float*)d_in[5];
    const float* A_log    = (const float*)d_in[6];
    const float* Dvec     = (const float*)d_in[7];
    float* out = (float*)d_out;

    // fp32 workspace
    float* ws_Bu    = (float*)d_ws;                       // M*S
    float* ws_delta = ws_Bu + (size_t)M * S;              // M
    float* ws_cP    = ws_delta + M;                       // Bb*S*NCH
    float* ws_cH    = ws_cP + (size_t)Bb * S * NCH;
    float* ws_init  = ws_cH + (size_t)Bb * S * NCH;
    // bf16 workspace
    bf16_t* params_bf = (bf16_t*)(ws_init + (size_t)Bb * S * NCH); // M*PST
    bf16_t* x_bf      = params_bf + (size_t)M * PST;      // M*Dm
    bf16_t* hmod_bf   = x_bf;                             // M*S (alias; x_bf dead after gemv)
    bf16_t* xconv_bf  = x_bf + (size_t)M * Dm;            // M*Dm
    bf16_t* Wx_bf     = xconv_bf + (size_t)M * Dm;        // NP*Dm (1025 rows)
    bf16_t* Win_bf    = Wx_bf + (size_t)NP * Dm;          // S*Dm
    bf16_t* Wout_bf   = Win_bf + (size_t)S * Dm;          // Dm*S

    hipFuncSetAttribute((const void*)gemm8p<0>,
                        hipFuncAttributeMaxDynamicSharedMemorySize, 131072);
    hipFuncSetAttribute((const void*)gemm8p<2>,
                        hipFuncAttributeMaxDynamicSharedMemorySize, 131072);
    hipFuncSetAttribute((const void*)gemm8ph,
                        hipFuncAttributeMaxDynamicSharedMemorySize, 98304);

    // 1. weight bf16 conversions (x handled by fused conv)
    long wx8 = (long)NP * Dm / 8;
    f2b_kernel<<<(wx8 + 255) / 256, 256, 0, stream>>>(Wxproj, Wx_bf, wx8, (long)NP * Dm);
    long wi8 = (long)S * Dm / 8;
    f2b_kernel<<<(wi8 + 255) / 256, 256, 0, stream>>>(Winproj, Win_bf, wi8, (long)S * Dm);
    f2b_kernel<<<(wi8 + 255) / 256, 256, 0, stream>>>(Woutproj, Wout_bf, wi8, (long)Dm * S);

    // 2. fused conv: x -> xconv_bf + x_bf  (8 channels/thread, 16B stores)
    conv_fused8<<<(Bb * NTC * 256) / 256, 256, 0, stream>>>(
        x, conv_w, conv_b, xconv_bf, x_bf);

    // 3. GEMM1: params(bf16, stride 1024) = x @ Wxproj[0:1024]^T
    dim3 g1(M / 256, PST / 256);
    gemm8p<0><<<g1, 512, 131072, stream>>>(x_bf, Wx_bf, PST, Dm, Dm / 64,
                                           params_bf, nullptr, nullptr, nullptr);

    // 4. delta = softplus(x . Wxproj[1024])  — fused GEMV
    gemv_delta<<<M / 4, 256, 0, stream>>>(x_bf, Wx_bf + (size_t)PST * Dm, ws_delta);

    // 5. GEMM2: Bu = delta * Bmat * (x_conv @ Winproj^T)   (128x256 tiles)
    dim3 g2(M / 128, S / 256);
    gemm8ph<<<g2, 512, 98304, stream>>>(xconv_bf, Win_bf, S, Dm, Dm / 64,
                                        ws_Bu, ws_delta, params_bf);

    // 6. chunked scan; h_mod = Cmat*h -> bf16
    dim3 gs(S / 256, NCH, Bb);
    scan_pass1<<<gs, 256, 0, stream>>>(ws_Bu, ws_delta, A_log, ws_cP, ws_cH);
    scan_pass2<<<(Bb * S) / 256, 256, 0, stream>>>(ws_cP, ws_cH, ws_init);
    scan_pass3<<<gs, 256, 0, stream>>>(ws_Bu, ws_delta, params_bf, A_log,
                                       ws_init, hmod_bf);

    // 7. GEMM3: out = h_mod @ Woutproj^T + D * x_conv
    dim3 g3(M / 256, Dm / 256);
    gemm8p<2><<<g3, 512, 131072, stream>>>(hmod_bf, Wout_bf, Dm, S, S / 64,
                                           nullptr, out, Dvec, xconv_bf);
}